// Round 3
// baseline (4708.203 us; speedup 1.0000x reference)
//
#include <hip/hip_runtime.h>

#define T_STEPS 1024
#define BATCH 32
#define HID 512
#define GATES 2048   // 4*HID
#define KDIM 512     // input size == HID

typedef __attribute__((ext_vector_type(8))) short short8;
typedef __attribute__((ext_vector_type(4))) float floatx4;

__device__ __forceinline__ unsigned short f2bf(float f) {
  union { float f; unsigned u; } v; v.f = f;
  return (unsigned short)((v.u + 0x7FFFu + ((v.u >> 16) & 1u)) >> 16);
}
__device__ __forceinline__ float bf2f(unsigned short s) {
  union { unsigned u; float f; } v; v.u = ((unsigned)s) << 16;
  return v.f;
}
__device__ __forceinline__ float fsigmoid(float x) {
  return 1.0f / (1.0f + __expf(-x));
}
__device__ __forceinline__ float ftanh(float x) {
  return 2.0f / (1.0f + __expf(-2.0f * x)) - 1.0f;
}

// ---------------------------------------------------------------------------
// init: zero the (h|seq) dword ping-pong buffers with agent-scope stores so
// the persistent kernel's sc1 polls never see stale poison.
// Zero == (h=0 | seq=0), which is exactly what step-0 consumers poll for.
// ---------------------------------------------------------------------------
__global__ void init_kernel(unsigned* __restrict__ hbuf_u) {  // 65536 dwords
  int idx = blockIdx.x * 256 + threadIdx.x;     // 65536 threads
  __hip_atomic_store(&hbuf_u[idx], 0u, __ATOMIC_RELAXED, __HIP_MEMORY_SCOPE_AGENT);
}

// ---------------------------------------------------------------------------
// add bwd-direction buffer into out (split-store mode only)
// ---------------------------------------------------------------------------
__global__ void merge_kernel(float* __restrict__ out,
                             const float* __restrict__ add, int n4) {
  int i = blockIdx.x * 256 + threadIdx.x;
  int stride = gridDim.x * 256;
  for (; i < n4; i += stride) {
    float4 a = ((const float4*)add)[i];
    float4 o = ((float4*)out)[i];
    o.x += a.x; o.y += a.y; o.z += a.z; o.w += a.w;
    ((float4*)out)[i] = o;
  }
}

// ---------------------------------------------------------------------------
// xw_precompute: XWT[t][ub][g][b][u] = sum_k X[t][b][k] * Wih[g*512+ub*16+u][k]
// (no bias; biases are added in the pointwise stage).
// Grid: 2048 blocks = 64 t-chunks (16 t each) x 32 ub.  512 threads = 8 waves,
// wave w: gate nt = w&3, batch-half mh = w>>2; full K=512 per wave.
// mode: 1 = bf16 output, 2 = fp32 output.
// ---------------------------------------------------------------------------
__global__ __launch_bounds__(512) void xw_precompute(
    const float* __restrict__ X,           // [1024, 32, 512]
    const float* __restrict__ Wih,         // [2048, 512]
    void* __restrict__ xwt, int mode) {
  __shared__ unsigned short xs[32][520];

  const int tid = threadIdx.x;
  const int ub = blockIdx.x & 31;
  const int tc = blockIdx.x >> 5;        // 0..63
  const int u0 = ub * 16;
  const int w = tid >> 6, lane = tid & 63;
  const int nt = w & 3, mh = w >> 2;
  const int colx = lane & 15, q = lane >> 4;

  // B-fragments: full K=512 for gate nt, unit u0+colx (16 x short8 = 64 VGPR)
  short8 bw[16];
  {
    const float* wr = Wih + (size_t)(nt * HID + u0 + colx) * KDIM + q * 8;
#pragma unroll
    for (int ks = 0; ks < 16; ++ks) {
      float4 h0 = *(const float4*)(wr + ks * 32);
      float4 h1 = *(const float4*)(wr + ks * 32 + 4);
      union { unsigned short u[8]; short8 v; } pk;
      pk.u[0] = f2bf(h0.x); pk.u[1] = f2bf(h0.y); pk.u[2] = f2bf(h0.z); pk.u[3] = f2bf(h0.w);
      pk.u[4] = f2bf(h1.x); pk.u[5] = f2bf(h1.y); pk.u[6] = f2bf(h1.z); pk.u[7] = f2bf(h1.w);
      bw[ks] = pk.v;
    }
  }

  for (int tt = 0; tt < 16; ++tt) {
    const int t = tc * 16 + tt;
    // stage X[t] -> LDS bf16
    const float* xt = X + (size_t)t * BATCH * KDIM;
#pragma unroll
    for (int r = 0; r < 8; ++r) {
      int idx = tid + r * 512;
      float4 xv = *(const float4*)(xt + (size_t)(idx >> 7) * KDIM + (idx & 127) * 4);
      union { unsigned short u[4]; uint2 v; } p;
      p.u[0] = f2bf(xv.x); p.u[1] = f2bf(xv.y);
      p.u[2] = f2bf(xv.z); p.u[3] = f2bf(xv.w);
      *(uint2*)&xs[idx >> 7][(idx & 127) * 4] = p.v;
    }
    __syncthreads();

    floatx4 acc = {0.f, 0.f, 0.f, 0.f};
    {
      const unsigned short* ap = &xs[mh * 16 + colx][q * 8];
#pragma unroll
      for (int ks = 0; ks < 16; ++ks) {
        short8 a = *(const short8*)(ap + ks * 32);
        acc = __builtin_amdgcn_mfma_f32_16x16x32_bf16(a, bw[ks], acc, 0, 0, 0);
      }
    }

    // write: XWT[t][ub][nt][mh*16+q*4+r][colx]
    const size_t base = (((size_t)t * 32 + ub) * 4 + nt) * 512 +
                        (size_t)(mh * 16 + q * 4) * 16 + colx;
    if (mode == 2) {
      float* o = (float*)xwt;
#pragma unroll
      for (int r = 0; r < 4; ++r) o[base + r * 16] = acc[r];
    } else {
      unsigned short* o = (unsigned short*)xwt;
#pragma unroll
      for (int r = 0; r < 4; ++r) o[base + r * 16] = f2bf(acc[r]);
    }
    __syncthreads();   // xs reused next tt
  }
}

// ---------------------------------------------------------------------------
// Persistent bidirectional zoneout-LSTM. 64 blocks x 512 thr.
// blocks 0..31: forward, 32..63: backward. Block owns 16 hidden units
// (64 gate cols). W_hh fragments live in registers.
//
// h-exchange protocol (flagless, self-validating data):
//  - h is transmitted as dwords (bf16 h | step_seq<<16), seq = s+1, via
//    agent-scope (sc1) relaxed stores. No flags, no fences, no barriers
//    after publish.
//  - consumer at step s polls buffer s&1 directly: each thread loads its
//    16 qwords and checks every embedded seq == s; retries until fresh.
//    The successful iteration's loads ARE the staging loads.
//  - seq unique per step -> no ABA; ping-pong x2 overwrite-safe by
//    construction (publishing s+1 requires having consumed s from every
//    block, program-order before any buffer-s&1 reread).
//
// XWM: 0 = in-loop x-projection (fallback), 1/2 = precomputed XWT
// (bf16/fp32): per step each block reads its own contiguous 8 KB slice.
// ---------------------------------------------------------------------------
template <int XWM>
__global__ __launch_bounds__(512) void lstm_persist(
    const float* __restrict__ X,           // [1024, 32, 512]
    const float* __restrict__ Wih,         // [2048, 512]
    const float* __restrict__ Whh,         // [2048, 512]
    const float* __restrict__ bih,         // [2048]
    const float* __restrict__ bhh,         // [2048]
    float* __restrict__ out,               // [1024*32*512]
    unsigned* __restrict__ hw,             // [2][2][32][512] dwords (h|seq)
    float* __restrict__ obwd,              // bwd out buffer (split) or null
    const void* __restrict__ xwt) {        // precomputed xw or null
  __shared__ unsigned short xs[32][520];   // staged x(t) bf16 (XWM==0 only)
  __shared__ unsigned short hs[32][520];   // staged h(s-1) bf16, +8 pad
  __shared__ float gp[2][32][64];          // gate partials per k-half

  const int tid = threadIdx.x;
  const int bid = blockIdx.x;
  const int dir = bid >> 5;
  const int bsl = bid & 31;
  const int u0 = bsl * 16;

  unsigned* hwD = hw + dir * 2 * (BATCH * HID);   // per-direction dword region

  const int w = tid >> 6, lane = tid & 63;
  const int kh = w >> 2;   // k-half: [kh*256, kh*256+256)
  const int nt = w & 3;    // gate index (16-col n-tile)
  const int colx = lane & 15, q = lane >> 4;

  // Preload this wave's W_hh B-fragments (and W_ih if in-loop x path).
  short8 bwh[8], bwx[8];
  {
    const size_t roff = (size_t)(nt * HID + u0 + colx) * KDIM + kh * 256 + q * 8;
    const float* wrh = Whh + roff;
#pragma unroll
    for (int ks = 0; ks < 8; ++ks) {
      float4 h0 = *(const float4*)(wrh + ks * 32);
      float4 h1 = *(const float4*)(wrh + ks * 32 + 4);
      union { unsigned short u[8]; short8 v; } pk;
      pk.u[0] = f2bf(h0.x); pk.u[1] = f2bf(h0.y); pk.u[2] = f2bf(h0.z); pk.u[3] = f2bf(h0.w);
      pk.u[4] = f2bf(h1.x); pk.u[5] = f2bf(h1.y); pk.u[6] = f2bf(h1.z); pk.u[7] = f2bf(h1.w);
      bwh[ks] = pk.v;
    }
    if (XWM == 0) {
      const float* wrx = Wih + roff;
#pragma unroll
      for (int ks = 0; ks < 8; ++ks) {
        float4 x0 = *(const float4*)(wrx + ks * 32);
        float4 x1 = *(const float4*)(wrx + ks * 32 + 4);
        union { unsigned short u[8]; short8 v; } px;
        px.u[0] = f2bf(x0.x); px.u[1] = f2bf(x0.y); px.u[2] = f2bf(x0.z); px.u[3] = f2bf(x0.w);
        px.u[4] = f2bf(x1.x); px.u[5] = f2bf(x1.y); px.u[6] = f2bf(x1.z); px.u[7] = f2bf(x1.w);
        bwx[ks] = px.v;
      }
    }
  }

  // Per-thread pointwise assignment: batch b, unit u (global col u0+u)
  const int b = tid >> 4, u = tid & 15;
  const float bias_i = bih[0 * HID + u0 + u] + bhh[0 * HID + u0 + u];
  const float bias_f = bih[1 * HID + u0 + u] + bhh[1 * HID + u0 + u];
  const float bias_g = bih[2 * HID + u0 + u] + bhh[2 * HID + u0 + u];
  const float bias_o = bih[3 * HID + u0 + u] + bhh[3 * HID + u0 + u];

  float c_st = 0.f, h_prev = 0.f;

  float* odst = nullptr;
  if (obwd) odst = dir ? obwd : out;   // split-store mode

  // ---- prologue (XWM==0): prefetch x(t0) into registers ----
  float4 xr[8];
  if (XWM == 0) {
    const int t0 = dir ? (T_STEPS - 1) : 0;
    const float* xt = X + (size_t)t0 * BATCH * KDIM;
#pragma unroll
    for (int r = 0; r < 8; ++r) {
      int idx = tid + r * 512;
      xr[r] = *(const float4*)(xt + (size_t)(idx >> 7) * KDIM + (idx & 127) * 4);
    }
  }

  for (int s = 0; s < T_STEPS; ++s) {
    const int t = dir ? (T_STEPS - 1 - s) : s;

    floatx4 acc0 = {0.f, 0.f, 0.f, 0.f}, acc1 = {0.f, 0.f, 0.f, 0.f};
    float xw4[4];

    if (XWM == 0) {
      // ---- convert prefetched x(t) -> LDS bf16 ----
#pragma unroll
      for (int r = 0; r < 8; ++r) {
        int idx = tid + r * 512;
        union { unsigned short u[4]; uint2 v; } p;
        p.u[0] = f2bf(xr[r].x); p.u[1] = f2bf(xr[r].y);
        p.u[2] = f2bf(xr[r].z); p.u[3] = f2bf(xr[r].w);
        *(uint2*)&xs[idx >> 7][(idx & 127) * 4] = p.v;
      }
      __syncthreads();   // B1

      // ---- x-projection MFMAs ----
      {
        const unsigned short* a0p = &xs[colx][kh * 256 + q * 8];
        const unsigned short* a1p = &xs[16 + colx][kh * 256 + q * 8];
#pragma unroll
        for (int ks = 0; ks < 8; ++ks) {
          short8 a0 = *(const short8*)(a0p + ks * 32);
          short8 a1 = *(const short8*)(a1p + ks * 32);
          acc0 = __builtin_amdgcn_mfma_f32_16x16x32_bf16(a0, bwx[ks], acc0, 0, 0, 0);
          acc1 = __builtin_amdgcn_mfma_f32_16x16x32_bf16(a1, bwx[ks], acc1, 0, 0, 0);
        }
      }

      // ---- issue x(t+1) prefetch; completes during the data poll ----
      {
        const int sn = (s + 1 < T_STEPS) ? (s + 1) : s;
        const int tn = dir ? (T_STEPS - 1 - sn) : sn;
        const float* xt = X + (size_t)tn * BATCH * KDIM;
#pragma unroll
        for (int r = 0; r < 8; ++r) {
          int idx = tid + r * 512;
          xr[r] = *(const float4*)(xt + (size_t)(idx >> 7) * KDIM + (idx & 127) * 4);
        }
      }
    } else {
      // ---- issue this block's 8 KB xw slice loads; they complete during
      //      the poll's vmcnt drain, long before the pointwise consumes them.
      if (XWM == 2) {
        const float* xwp = (const float*)xwt + (((size_t)t * 32 + bsl) * 4) * 512 + tid;
#pragma unroll
        for (int g = 0; g < 4; ++g) xw4[g] = xwp[g * 512];
      } else {
        const unsigned short* xwp =
            (const unsigned short*)xwt + (((size_t)t * 32 + bsl) * 4) * 512 + tid;
#pragma unroll
        for (int g = 0; g < 4; ++g) xw4[g] = bf2f(xwp[g * 512]);
      }
    }

    // ---- wait + stage: poll h(s-1) data directly (self-validating seq) ----
    {
      const unsigned long long* hq =
          (const unsigned long long*)(hwD + (s & 1) * (BATCH * HID));
      const unsigned long long rep = ((unsigned long long)(unsigned)s << 16) |
                                     ((unsigned long long)(unsigned)s << 48);
      unsigned long long v[16];
      for (;;) {
#pragma unroll
        for (int r = 0; r < 16; ++r)
          v[r] = __hip_atomic_load(&hq[tid + r * 512], __ATOMIC_RELAXED,
                                   __HIP_MEMORY_SCOPE_AGENT);
        unsigned long long bad = 0;
#pragma unroll
        for (int r = 0; r < 16; ++r) bad |= (v[r] ^ rep);
        if (!(bad & 0xFFFF0000FFFF0000ULL)) break;   // all seqs fresh
        __builtin_amdgcn_s_sleep(1);                 // stragglers in flight
      }
#pragma unroll
      for (int r = 0; r < 16; ++r) {
        int g = tid + r * 512;                       // qword index 0..8191
        unsigned packed = (unsigned)(v[r] & 0xFFFFu) |
                          ((unsigned)(v[r] >> 32) << 16);
        *(unsigned*)&hs[g >> 8][(g & 255) * 2] = packed;
      }
    }
    __syncthreads();   // B2 (stage complete before h-MFMA reads)

    // ---- h-projection MFMAs ----
    {
      const unsigned short* a0p = &hs[colx][kh * 256 + q * 8];
      const unsigned short* a1p = &hs[16 + colx][kh * 256 + q * 8];
#pragma unroll
      for (int ks = 0; ks < 8; ++ks) {
        short8 a0 = *(const short8*)(a0p + ks * 32);
        short8 a1 = *(const short8*)(a1p + ks * 32);
        acc0 = __builtin_amdgcn_mfma_f32_16x16x32_bf16(a0, bwh[ks], acc0, 0, 0, 0);
        acc1 = __builtin_amdgcn_mfma_f32_16x16x32_bf16(a1, bwh[ks], acc1, 0, 0, 0);
      }
    }
#pragma unroll
    for (int r = 0; r < 4; ++r) {
      gp[kh][q * 4 + r][nt * 16 + colx] = acc0[r];
      gp[kh][16 + q * 4 + r][nt * 16 + colx] = acc1[r];
    }
    __syncthreads();   // B3

    // ---- pointwise LSTM cell + zoneout for (b, u) ----
    float gi = gp[0][b][u]      + gp[1][b][u]      + bias_i;
    float gf = gp[0][b][16 + u] + gp[1][b][16 + u] + bias_f;
    float gg = gp[0][b][32 + u] + gp[1][b][32 + u] + bias_g;
    float go = gp[0][b][48 + u] + gp[1][b][48 + u] + bias_o;
    if (XWM != 0) {
      gi += xw4[0]; gf += xw4[1]; gg += xw4[2]; go += xw4[3];
    }
    float si = fsigmoid(gi);
    float sf = fsigmoid(gf);
    float tg = ftanh(gg);
    float so = fsigmoid(go);
    float c_new = sf * c_st + si * tg;
    float h_new = so * ftanh(c_new);
    c_st = 0.9f * c_new + 0.1f * c_st;
    float h = 0.9f * h_new + 0.1f * h_prev;
    h_prev = h;

    // ---- publish h: per-thread (h|seq) dword, sc1; no barrier, no flag ----
    {
      unsigned D = (unsigned)f2bf(h) | ((unsigned)(s + 1) << 16);
      unsigned* hop = hwD + ((s + 1) & 1) * (BATCH * HID);
      __hip_atomic_store(&hop[b * HID + u0 + u], D,
                         __ATOMIC_RELAXED, __HIP_MEMORY_SCOPE_AGENT);
    }

    // off the critical path: output write
    {
      size_t oidx = (size_t)(t * BATCH + b) * HID + u0 + u;
      if (odst) __builtin_nontemporal_store(h, &odst[oidx]);
      else atomicAdd(out + oidx, h);   // fallback: tiny workspace
    }
  }
}

// ---------------------------------------------------------------------------
extern "C" void kernel_launch(void* const* d_in, const int* in_sizes, int n_in,
                              void* d_out, int out_size, void* d_ws, size_t ws_size,
                              hipStream_t stream) {
  const float* X   = (const float*)d_in[0];
  const float* Wih = (const float*)d_in[1];
  const float* Whh = (const float*)d_in[2];
  const float* bih = (const float*)d_in[3];
  const float* bhh = (const float*)d_in[4];
  float* out = (float*)d_out;

  // workspace layout:
  //   [0, 256KB):        hw = [2 dir][2 buf][32][512] (h|seq) dwords
  //   [1MB, 65MB):       bwd-direction output buffer (split-store mode)
  //   [66MB, 66MB+XWT):  precomputed xw, fp32 (256MB) or bf16 (128MB)
  unsigned* hw = (unsigned*)d_ws;                     // 65536 dwords

  const size_t OB_OFF = (size_t)1 << 20;
  const size_t XW_OFF = (size_t)66 << 20;
  const size_t OB_BYTES = (size_t)T_STEPS * BATCH * HID * sizeof(float); // 64MB
  const size_t XW_ELEMS = (size_t)T_STEPS * 32 * 4 * 32 * 16;            // 67.1M

  float* obwd = nullptr;
  if (ws_size >= OB_OFF + OB_BYTES)
    obwd = (float*)((char*)d_ws + OB_OFF);

  int xwm = 0;
  void* xwt = nullptr;
  if (obwd) {
    if (ws_size >= XW_OFF + XW_ELEMS * sizeof(float)) {
      xwm = 2; xwt = (char*)d_ws + XW_OFF;
    } else if (ws_size >= XW_OFF + XW_ELEMS * sizeof(unsigned short)) {
      xwm = 1; xwt = (char*)d_ws + XW_OFF;
    }
  }

  if (!obwd)   // fallback: atomicAdd accumulation needs zeroed out
    hipMemsetAsync(d_out, 0, (size_t)out_size * sizeof(float), stream);

  hipLaunchKernelGGL(init_kernel, dim3(256), dim3(256), 0, stream, hw);
  if (xwm)
    hipLaunchKernelGGL(xw_precompute, dim3(2048), dim3(512), 0, stream,
                       X, Wih, xwt, xwm);

  if (xwm == 2)
    hipLaunchKernelGGL(HIP_KERNEL_NAME(lstm_persist<2>), dim3(64), dim3(512), 0,
                       stream, X, Wih, Whh, bih, bhh, out, hw, obwd, xwt);
  else if (xwm == 1)
    hipLaunchKernelGGL(HIP_KERNEL_NAME(lstm_persist<1>), dim3(64), dim3(512), 0,
                       stream, X, Wih, Whh, bih, bhh, out, hw, obwd, xwt);
  else
    hipLaunchKernelGGL(HIP_KERNEL_NAME(lstm_persist<0>), dim3(64), dim3(512), 0,
                       stream, X, Wih, Whh, bih, bhh, out, hw, obwd, xwt);

  if (obwd)
    hipLaunchKernelGGL(merge_kernel, dim3(2048), dim3(256), 0, stream,
                       out, obwd, (T_STEPS * BATCH * HID) / 4);
}

// Round 4
// 4252.302 us; speedup vs baseline: 1.1072x; 1.1072x over previous
//
#include <hip/hip_runtime.h>

#define T_STEPS 1024
#define BATCH 32
#define HID 512
#define GATES 2048   // 4*HID
#define KDIM 512     // input size == HID

typedef __attribute__((ext_vector_type(8))) short short8;
typedef __attribute__((ext_vector_type(4))) float floatx4;

__device__ __forceinline__ unsigned short f2bf(float f) {
  union { float f; unsigned u; } v; v.f = f;
  return (unsigned short)((v.u + 0x7FFFu + ((v.u >> 16) & 1u)) >> 16);
}
__device__ __forceinline__ float fsigmoid(float x) {
  return 1.0f / (1.0f + __expf(-x));
}
__device__ __forceinline__ float ftanh(float x) {
  return 2.0f / (1.0f + __expf(-2.0f * x)) - 1.0f;
}

// ---------------------------------------------------------------------------
// init: zero the (h|seq) dword ping-pong buffers with agent-scope stores so
// the persistent kernel's sc1 polls never see stale poison.
// Zero == (h=0 | seq=0), which is exactly what step-0 consumers poll for.
// ---------------------------------------------------------------------------
__global__ void init_kernel(unsigned* __restrict__ hbuf_u) {  // 65536 dwords
  int idx = blockIdx.x * 256 + threadIdx.x;     // 65536 threads
  __hip_atomic_store(&hbuf_u[idx], 0u, __ATOMIC_RELAXED, __HIP_MEMORY_SCOPE_AGENT);
}

// ---------------------------------------------------------------------------
// add bwd-direction buffer into out (split-store mode only)
// ---------------------------------------------------------------------------
__global__ void merge_kernel(float* __restrict__ out,
                             const float* __restrict__ add, int n4) {
  int i = blockIdx.x * 256 + threadIdx.x;
  int stride = gridDim.x * 256;
  for (; i < n4; i += stride) {
    float4 a = ((const float4*)add)[i];
    float4 o = ((float4*)out)[i];
    o.x += a.x; o.y += a.y; o.z += a.z; o.w += a.w;
    ((float4*)out)[i] = o;
  }
}

// ---------------------------------------------------------------------------
// Persistent bidirectional zoneout-LSTM. 64 blocks x 512 thr.
// blocks 0..31: forward, 32..63: backward. Block owns 16 hidden units
// (64 gate cols). W_hh / W_ih fragments live in registers.
//
// h-exchange protocol (flagless, self-validating data, cheap-sentinel poll):
//  - h is transmitted as dwords (bf16 h | step_seq<<16), seq = s+1, via
//    agent-scope (sc1) relaxed stores. No flags, no fences, no barriers
//    after publish.
//  - layout property: thread tid's 16 poll qwords {tid + r*512} all live at
//    dword column (2*tid)&511, i.e. belong to EXACTLY ONE producer block
//    ((col>>4)&31). So r=0 is a valid per-producer sentinel for the whole
//    per-thread region.
//  - consumer at step s: pre-issue loads r=1..15 (overlap), spin on the r=0
//    qword only (8 B/thread/iter -> 16x less poll traffic than full-region
//    re-read; LLC contention was the R2/R3 step-time floor), then verify
//    embedded seqs of the pre-issued loads; rare full retry if the
//    producer's store burst was mid-flight.
//  - seq unique per step -> no ABA; ping-pong x2 overwrite-safe by
//    construction (publishing s+1 requires every thread of every block
//    having verified seq-s across the full buffer, program-order before
//    any buffer-(s+1)&1 write).
// ---------------------------------------------------------------------------
__global__ __launch_bounds__(512) void lstm_persist(
    const float* __restrict__ X,           // [1024, 32, 512]
    const float* __restrict__ Wih,         // [2048, 512]
    const float* __restrict__ Whh,         // [2048, 512]
    const float* __restrict__ bih,         // [2048]
    const float* __restrict__ bhh,         // [2048]
    float* __restrict__ out,               // [1024*32*512]
    unsigned* __restrict__ hw,             // [2][2][32][512] dwords (h|seq)
    float* __restrict__ obwd) {            // bwd out buffer (split) or null
  __shared__ unsigned short xs[32][520];   // staged x(t) bf16, +8 pad
  __shared__ unsigned short hs[32][520];   // staged h(s-1) bf16, +8 pad
  __shared__ float gp[2][32][64];          // gate partials per k-half

  const int tid = threadIdx.x;
  const int bid = blockIdx.x;
  const int dir = bid >> 5;
  const int bsl = bid & 31;
  const int u0 = bsl * 16;

  unsigned* hwD = hw + dir * 2 * (BATCH * HID);   // per-direction dword region

  const int w = tid >> 6, lane = tid & 63;
  const int kh = w >> 2;   // k-half: [kh*256, kh*256+256)
  const int nt = w & 3;    // gate index (16-col n-tile)
  const int colx = lane & 15, q = lane >> 4;

  // Preload this wave's B-fragments into registers: gate nt, unit u0+colx.
  short8 bwh[8], bwx[8];
  {
    const size_t roff = (size_t)(nt * HID + u0 + colx) * KDIM + kh * 256 + q * 8;
    const float* wrh = Whh + roff;
    const float* wrx = Wih + roff;
#pragma unroll
    for (int ks = 0; ks < 8; ++ks) {
      float4 h0 = *(const float4*)(wrh + ks * 32);
      float4 h1 = *(const float4*)(wrh + ks * 32 + 4);
      union { unsigned short u[8]; short8 v; } pk;
      pk.u[0] = f2bf(h0.x); pk.u[1] = f2bf(h0.y); pk.u[2] = f2bf(h0.z); pk.u[3] = f2bf(h0.w);
      pk.u[4] = f2bf(h1.x); pk.u[5] = f2bf(h1.y); pk.u[6] = f2bf(h1.z); pk.u[7] = f2bf(h1.w);
      bwh[ks] = pk.v;
      float4 x0 = *(const float4*)(wrx + ks * 32);
      float4 x1 = *(const float4*)(wrx + ks * 32 + 4);
      union { unsigned short u[8]; short8 v; } px;
      px.u[0] = f2bf(x0.x); px.u[1] = f2bf(x0.y); px.u[2] = f2bf(x0.z); px.u[3] = f2bf(x0.w);
      px.u[4] = f2bf(x1.x); px.u[5] = f2bf(x1.y); px.u[6] = f2bf(x1.z); px.u[7] = f2bf(x1.w);
      bwx[ks] = px.v;
    }
  }

  // Per-thread pointwise assignment: batch b, unit u (global col u0+u)
  const int b = tid >> 4, u = tid & 15;
  const float bias_i = bih[0 * HID + u0 + u] + bhh[0 * HID + u0 + u];
  const float bias_f = bih[1 * HID + u0 + u] + bhh[1 * HID + u0 + u];
  const float bias_g = bih[2 * HID + u0 + u] + bhh[2 * HID + u0 + u];
  const float bias_o = bih[3 * HID + u0 + u] + bhh[3 * HID + u0 + u];

  float c_st = 0.f, h_prev = 0.f;

  float* odst = nullptr;
  if (obwd) odst = dir ? obwd : out;   // split-store mode

  // ---- prologue: prefetch x(t0) into registers ----
  float4 xr[8];
  {
    const int t0 = dir ? (T_STEPS - 1) : 0;
    const float* xt = X + (size_t)t0 * BATCH * KDIM;
#pragma unroll
    for (int r = 0; r < 8; ++r) {
      int idx = tid + r * 512;
      xr[r] = *(const float4*)(xt + (size_t)(idx >> 7) * KDIM + (idx & 127) * 4);
    }
  }

  for (int s = 0; s < T_STEPS; ++s) {
    const int t = dir ? (T_STEPS - 1 - s) : s;

    // ---- convert prefetched x(t) -> LDS bf16 ----
#pragma unroll
    for (int r = 0; r < 8; ++r) {
      int idx = tid + r * 512;
      union { unsigned short u[4]; uint2 v; } p;
      p.u[0] = f2bf(xr[r].x); p.u[1] = f2bf(xr[r].y);
      p.u[2] = f2bf(xr[r].z); p.u[3] = f2bf(xr[r].w);
      *(uint2*)&xs[idx >> 7][(idx & 127) * 4] = p.v;
    }
    __syncthreads();   // B1

    // ---- x-projection MFMAs (independent of h) ----
    floatx4 acc0 = {0.f, 0.f, 0.f, 0.f}, acc1 = {0.f, 0.f, 0.f, 0.f};
    {
      const unsigned short* a0p = &xs[colx][kh * 256 + q * 8];
      const unsigned short* a1p = &xs[16 + colx][kh * 256 + q * 8];
#pragma unroll
      for (int ks = 0; ks < 8; ++ks) {
        short8 a0 = *(const short8*)(a0p + ks * 32);
        short8 a1 = *(const short8*)(a1p + ks * 32);
        acc0 = __builtin_amdgcn_mfma_f32_16x16x32_bf16(a0, bwx[ks], acc0, 0, 0, 0);
        acc1 = __builtin_amdgcn_mfma_f32_16x16x32_bf16(a1, bwx[ks], acc1, 0, 0, 0);
      }
    }

    // ---- issue x(t+1) prefetch; completes during the data poll ----
    {
      const int sn = (s + 1 < T_STEPS) ? (s + 1) : s;
      const int tn = dir ? (T_STEPS - 1 - sn) : sn;
      const float* xt = X + (size_t)tn * BATCH * KDIM;
#pragma unroll
      for (int r = 0; r < 8; ++r) {
        int idx = tid + r * 512;
        xr[r] = *(const float4*)(xt + (size_t)(idx >> 7) * KDIM + (idx & 127) * 4);
      }
    }

    // ---- wait + stage: cheap-sentinel poll, then verified bulk read ----
    {
      const unsigned long long* hq =
          (const unsigned long long*)(hwD + (s & 1) * (BATCH * HID));
      const unsigned long long rep = ((unsigned long long)(unsigned)s << 16) |
                                     ((unsigned long long)(unsigned)s << 48);
      const unsigned long long msk = 0xFFFF0000FFFF0000ULL;
      unsigned long long v[16];

      // pre-issue bulk loads r=1..15 (they fly during the sentinel spin)
#pragma unroll
      for (int r = 1; r < 16; ++r)
        v[r] = __hip_atomic_load(&hq[tid + r * 512], __ATOMIC_RELAXED,
                                 __HIP_MEMORY_SCOPE_AGENT);
      // sentinel spin: 8 B/thread/iter; my whole region is ONE producer,
      // so r=0 fresh => that producer reached its step-s publish.
      for (;;) {
        v[0] = __hip_atomic_load(&hq[tid], __ATOMIC_RELAXED,
                                 __HIP_MEMORY_SCOPE_AGENT);
        if (!((v[0] ^ rep) & msk)) break;
      }
      // verify pre-issued loads; rare retry if the store burst was mid-flight
      for (;;) {
        unsigned long long bad = 0;
#pragma unroll
        for (int r = 1; r < 16; ++r) bad |= (v[r] ^ rep);
        if (!(bad & msk)) break;
        __builtin_amdgcn_s_sleep(1);
#pragma unroll
        for (int r = 1; r < 16; ++r)
          v[r] = __hip_atomic_load(&hq[tid + r * 512], __ATOMIC_RELAXED,
                                   __HIP_MEMORY_SCOPE_AGENT);
      }
#pragma unroll
      for (int r = 0; r < 16; ++r) {
        int g = tid + r * 512;                       // qword index 0..8191
        unsigned packed = (unsigned)(v[r] & 0xFFFFu) |
                          ((unsigned)(v[r] >> 32) << 16);
        *(unsigned*)&hs[g >> 8][(g & 255) * 2] = packed;
      }
    }
    __syncthreads();   // B2 (stage complete before h-MFMA reads)

    // ---- h-projection MFMAs ----
    {
      const unsigned short* a0p = &hs[colx][kh * 256 + q * 8];
      const unsigned short* a1p = &hs[16 + colx][kh * 256 + q * 8];
#pragma unroll
      for (int ks = 0; ks < 8; ++ks) {
        short8 a0 = *(const short8*)(a0p + ks * 32);
        short8 a1 = *(const short8*)(a1p + ks * 32);
        acc0 = __builtin_amdgcn_mfma_f32_16x16x32_bf16(a0, bwh[ks], acc0, 0, 0, 0);
        acc1 = __builtin_amdgcn_mfma_f32_16x16x32_bf16(a1, bwh[ks], acc1, 0, 0, 0);
      }
    }
#pragma unroll
    for (int r = 0; r < 4; ++r) {
      gp[kh][q * 4 + r][nt * 16 + colx] = acc0[r];
      gp[kh][16 + q * 4 + r][nt * 16 + colx] = acc1[r];
    }
    __syncthreads();   // B3

    // ---- pointwise LSTM cell + zoneout for (b, u) ----
    float gi = gp[0][b][u]      + gp[1][b][u]      + bias_i;
    float gf = gp[0][b][16 + u] + gp[1][b][16 + u] + bias_f;
    float gg = gp[0][b][32 + u] + gp[1][b][32 + u] + bias_g;
    float go = gp[0][b][48 + u] + gp[1][b][48 + u] + bias_o;
    float si = fsigmoid(gi);
    float sf = fsigmoid(gf);
    float tg = ftanh(gg);
    float so = fsigmoid(go);
    float c_new = sf * c_st + si * tg;
    float h_new = so * ftanh(c_new);
    c_st = 0.9f * c_new + 0.1f * c_st;
    float h = 0.9f * h_new + 0.1f * h_prev;
    h_prev = h;

    // ---- publish h: per-thread (h|seq) dword, sc1; no barrier, no flag ----
    {
      unsigned D = (unsigned)f2bf(h) | ((unsigned)(s + 1) << 16);
      unsigned* hop = hwD + ((s + 1) & 1) * (BATCH * HID);
      __hip_atomic_store(&hop[b * HID + u0 + u], D,
                         __ATOMIC_RELAXED, __HIP_MEMORY_SCOPE_AGENT);
    }

    // off the critical path: output write
    {
      size_t oidx = (size_t)(t * BATCH + b) * HID + u0 + u;
      if (odst) __builtin_nontemporal_store(h, &odst[oidx]);
      else atomicAdd(out + oidx, h);   // fallback: tiny workspace
    }
  }
}

// ---------------------------------------------------------------------------
extern "C" void kernel_launch(void* const* d_in, const int* in_sizes, int n_in,
                              void* d_out, int out_size, void* d_ws, size_t ws_size,
                              hipStream_t stream) {
  const float* X   = (const float*)d_in[0];
  const float* Wih = (const float*)d_in[1];
  const float* Whh = (const float*)d_in[2];
  const float* bih = (const float*)d_in[3];
  const float* bhh = (const float*)d_in[4];
  float* out = (float*)d_out;

  // workspace layout:
  //   [0, 256KB):      hw = [2 dir][2 buf][32][512] (h|seq) dwords (256 KB)
  //   [1MB, 65MB):     bwd-direction output buffer (split-store mode)
  unsigned* hw = (unsigned*)d_ws;                     // 65536 dwords

  const size_t OB_OFF = (size_t)1 << 20;
  const size_t OB_BYTES = (size_t)T_STEPS * BATCH * HID * sizeof(float); // 64MB

  float* obwd = nullptr;
  if (ws_size >= OB_OFF + OB_BYTES)
    obwd = (float*)((char*)d_ws + OB_OFF);

  if (!obwd)   // fallback: atomicAdd accumulation needs zeroed out
    hipMemsetAsync(d_out, 0, (size_t)out_size * sizeof(float), stream);

  hipLaunchKernelGGL(init_kernel, dim3(256), dim3(256), 0, stream, hw);
  hipLaunchKernelGGL(lstm_persist, dim3(64), dim3(512), 0, stream,
                     X, Wih, Whh, bih, bhh, out, hw, obwd);
  if (obwd)
    hipLaunchKernelGGL(merge_kernel, dim3(2048), dim3(256), 0, stream,
                       out, obwd, (T_STEPS * BATCH * HID) / 4);
}

// Round 5
// 4239.554 us; speedup vs baseline: 1.1105x; 1.0030x over previous
//
#include <hip/hip_runtime.h>

#define T_STEPS 1024
#define BATCH 32
#define HID 512
#define GATES 2048   // 4*HID
#define KDIM 512     // input size == HID
#define NBLK 512     // launched blocks (claim pool)

typedef __attribute__((ext_vector_type(8))) short short8;
typedef __attribute__((ext_vector_type(4))) float floatx4;
typedef unsigned long long u64;

__device__ __forceinline__ unsigned short f2bf(float f) {
  union { float f; unsigned u; } v; v.f = f;
  return (unsigned short)((v.u + 0x7FFFu + ((v.u >> 16) & 1u)) >> 16);
}
__device__ __forceinline__ float fsigmoid(float x) {
  return 1.0f / (1.0f + __expf(-x));
}
__device__ __forceinline__ float ftanh(float x) {
  return 2.0f / (1.0f + __expf(-2.0f * x)) - 1.0f;
}

// ---- scoped 8B load/store helpers -----------------------------------------
// WG=true : sc0 only  -> bypass L1, coherence point = this XCD's L2
// WG=false: sc0 sc1   -> bypass L1+L2, coherence point = LLC (agent-safe)
template <bool WG>
__device__ __forceinline__ u64 ldq(const u64* p) {
  u64 r;
  if (WG)
    asm volatile("global_load_dwordx2 %0, %1, off sc0\n\ts_waitcnt vmcnt(0)"
                 : "=v"(r) : "v"(p) : "memory");
  else
    asm volatile("global_load_dwordx2 %0, %1, off sc0 sc1\n\ts_waitcnt vmcnt(0)"
                 : "=v"(r) : "v"(p) : "memory");
  return r;
}
template <bool WG>
__device__ __forceinline__ void stq(u64* p, u64 v) {
  if (WG)
    asm volatile("global_store_dwordx2 %0, %1, off sc0" :: "v"(p), "v"(v) : "memory");
  else
    asm volatile("global_store_dwordx2 %0, %1, off sc0 sc1" :: "v"(p), "v"(v) : "memory");
}
__device__ __forceinline__ void waitv0() {
  asm volatile("s_waitcnt vmcnt(0)" ::: "memory");
}

// 16 strided qword loads (stride 512 qwords) + single waitcnt.
template <bool WG>
__device__ __forceinline__ void bulk16(const u64* b0, u64 v[16]) {
  const u64 *p0 = b0,        *p1 = b0 + 512,  *p2 = b0 + 1024, *p3 = b0 + 1536,
            *p4 = b0 + 2048, *p5 = b0 + 2560, *p6 = b0 + 3072, *p7 = b0 + 3584,
            *p8 = b0 + 4096, *p9 = b0 + 4608, *p10 = b0 + 5120, *p11 = b0 + 5632,
            *p12 = b0 + 6144, *p13 = b0 + 6656, *p14 = b0 + 7168, *p15 = b0 + 7680;
  if (WG)
    asm volatile(
        "global_load_dwordx2 %0, %16, off sc0\n\t"
        "global_load_dwordx2 %1, %17, off sc0\n\t"
        "global_load_dwordx2 %2, %18, off sc0\n\t"
        "global_load_dwordx2 %3, %19, off sc0\n\t"
        "global_load_dwordx2 %4, %20, off sc0\n\t"
        "global_load_dwordx2 %5, %21, off sc0\n\t"
        "global_load_dwordx2 %6, %22, off sc0\n\t"
        "global_load_dwordx2 %7, %23, off sc0\n\t"
        "global_load_dwordx2 %8, %24, off sc0\n\t"
        "global_load_dwordx2 %9, %25, off sc0\n\t"
        "global_load_dwordx2 %10, %26, off sc0\n\t"
        "global_load_dwordx2 %11, %27, off sc0\n\t"
        "global_load_dwordx2 %12, %28, off sc0\n\t"
        "global_load_dwordx2 %13, %29, off sc0\n\t"
        "global_load_dwordx2 %14, %30, off sc0\n\t"
        "global_load_dwordx2 %15, %31, off sc0\n\t"
        "s_waitcnt vmcnt(0)"
        : "=&v"(v[0]), "=&v"(v[1]), "=&v"(v[2]), "=&v"(v[3]), "=&v"(v[4]),
          "=&v"(v[5]), "=&v"(v[6]), "=&v"(v[7]), "=&v"(v[8]), "=&v"(v[9]),
          "=&v"(v[10]), "=&v"(v[11]), "=&v"(v[12]), "=&v"(v[13]), "=&v"(v[14]),
          "=&v"(v[15])
        : "v"(p0), "v"(p1), "v"(p2), "v"(p3), "v"(p4), "v"(p5), "v"(p6), "v"(p7),
          "v"(p8), "v"(p9), "v"(p10), "v"(p11), "v"(p12), "v"(p13), "v"(p14),
          "v"(p15)
        : "memory");
  else
    asm volatile(
        "global_load_dwordx2 %0, %16, off sc0 sc1\n\t"
        "global_load_dwordx2 %1, %17, off sc0 sc1\n\t"
        "global_load_dwordx2 %2, %18, off sc0 sc1\n\t"
        "global_load_dwordx2 %3, %19, off sc0 sc1\n\t"
        "global_load_dwordx2 %4, %20, off sc0 sc1\n\t"
        "global_load_dwordx2 %5, %21, off sc0 sc1\n\t"
        "global_load_dwordx2 %6, %22, off sc0 sc1\n\t"
        "global_load_dwordx2 %7, %23, off sc0 sc1\n\t"
        "global_load_dwordx2 %8, %24, off sc0 sc1\n\t"
        "global_load_dwordx2 %9, %25, off sc0 sc1\n\t"
        "global_load_dwordx2 %10, %26, off sc0 sc1\n\t"
        "global_load_dwordx2 %11, %27, off sc0 sc1\n\t"
        "global_load_dwordx2 %12, %28, off sc0 sc1\n\t"
        "global_load_dwordx2 %13, %29, off sc0 sc1\n\t"
        "global_load_dwordx2 %14, %30, off sc0 sc1\n\t"
        "global_load_dwordx2 %15, %31, off sc0 sc1\n\t"
        "s_waitcnt vmcnt(0)"
        : "=&v"(v[0]), "=&v"(v[1]), "=&v"(v[2]), "=&v"(v[3]), "=&v"(v[4]),
          "=&v"(v[5]), "=&v"(v[6]), "=&v"(v[7]), "=&v"(v[8]), "=&v"(v[9]),
          "=&v"(v[10]), "=&v"(v[11]), "=&v"(v[12]), "=&v"(v[13]), "=&v"(v[14]),
          "=&v"(v[15])
        : "v"(p0), "v"(p1), "v"(p2), "v"(p3), "v"(p4), "v"(p5), "v"(p6), "v"(p7),
          "v"(p8), "v"(p9), "v"(p10), "v"(p11), "v"(p12), "v"(p13), "v"(p14),
          "v"(p15)
        : "memory");
}

// ---------------------------------------------------------------------------
// init: zero claim-control block (sc1 so the persistent kernel's agent polls
// never see stale poison). hw buffers are zeroed by the claimed blocks
// themselves through the SAME path consumers read (sc0 or sc1).
// ---------------------------------------------------------------------------
__global__ void init_kernel(unsigned* __restrict__ ctrl) {  // 128 u32
  int idx = threadIdx.x;
  __hip_atomic_store(&ctrl[idx], 0u, __ATOMIC_RELAXED, __HIP_MEMORY_SCOPE_AGENT);
}

__global__ void merge_kernel(float* __restrict__ out,
                             const float* __restrict__ add, int n4) {
  int i = blockIdx.x * 256 + threadIdx.x;
  int stride = gridDim.x * 256;
  for (; i < n4; i += stride) {
    float4 a = ((const float4*)add)[i];
    float4 o = ((float4*)out)[i];
    o.x += a.x; o.y += a.y; o.z += a.z; o.w += a.w;
    ((float4*)out)[i] = o;
  }
}

// ---------------------------------------------------------------------------
// Main loop, templated on exchange scope.
// hw format: qword per unit-pair: dw0 = (bf16 h_even | bf16 h_odd<<16),
// dw1 = seq32 = epoch + step. Self-validating, flagless. Ping-pong x2.
// ---------------------------------------------------------------------------
template <bool WG>
__device__ __forceinline__ void run_loop(
    const float* __restrict__ X, const float* __restrict__ Wih,
    const float* __restrict__ Whh, const float* __restrict__ bih,
    const float* __restrict__ bhh, float* __restrict__ out,
    u64* __restrict__ hwq, float* __restrict__ obwd,
    unsigned* __restrict__ ctrl, int dir, int bsl, unsigned epoch,
    unsigned short (*xs)[520], unsigned short (*hs)[520], float (*gp)[32][64]) {
  const int tid = threadIdx.x;
  const int u0 = bsl * 16;
  u64* hwD = hwq + dir * 2 * 8192;   // [2 buf][32 b][256 qw]

  // ---- zero own slices in both ping buffers through the consumer path ----
  {
    int buf = tid >> 8, row = (tid >> 3) & 31, c = bsl * 8 + (tid & 7);
    stq<WG>(hwD + buf * 8192 + row * 256 + c, ((u64)epoch) << 32);
    waitv0();
  }
  if (tid == 0) {
    __hip_atomic_fetch_add(&ctrl[4 + dir], 1u, __ATOMIC_RELAXED, __HIP_MEMORY_SCOPE_AGENT);
    while (__hip_atomic_load(&ctrl[4 + dir], __ATOMIC_RELAXED, __HIP_MEMORY_SCOPE_AGENT) < 32u)
      __builtin_amdgcn_s_sleep(1);
  }
  __syncthreads();

  const int w = tid >> 6, lane = tid & 63;
  const int kh = w >> 2;
  const int nt = w & 3;
  const int colx = lane & 15, q = lane >> 4;

  short8 bwh[8], bwx[8];
  {
    const size_t roff = (size_t)(nt * HID + u0 + colx) * KDIM + kh * 256 + q * 8;
    const float* wrh = Whh + roff;
    const float* wrx = Wih + roff;
#pragma unroll
    for (int ks = 0; ks < 8; ++ks) {
      float4 h0 = *(const float4*)(wrh + ks * 32);
      float4 h1 = *(const float4*)(wrh + ks * 32 + 4);
      union { unsigned short u[8]; short8 v; } pk;
      pk.u[0] = f2bf(h0.x); pk.u[1] = f2bf(h0.y); pk.u[2] = f2bf(h0.z); pk.u[3] = f2bf(h0.w);
      pk.u[4] = f2bf(h1.x); pk.u[5] = f2bf(h1.y); pk.u[6] = f2bf(h1.z); pk.u[7] = f2bf(h1.w);
      bwh[ks] = pk.v;
      float4 x0 = *(const float4*)(wrx + ks * 32);
      float4 x1 = *(const float4*)(wrx + ks * 32 + 4);
      union { unsigned short u[8]; short8 v; } px;
      px.u[0] = f2bf(x0.x); px.u[1] = f2bf(x0.y); px.u[2] = f2bf(x0.z); px.u[3] = f2bf(x0.w);
      px.u[4] = f2bf(x1.x); px.u[5] = f2bf(x1.y); px.u[6] = f2bf(x1.z); px.u[7] = f2bf(x1.w);
      bwx[ks] = px.v;
    }
  }

  const int b = tid >> 4, u = tid & 15;
  const float bias_i = bih[0 * HID + u0 + u] + bhh[0 * HID + u0 + u];
  const float bias_f = bih[1 * HID + u0 + u] + bhh[1 * HID + u0 + u];
  const float bias_g = bih[2 * HID + u0 + u] + bhh[2 * HID + u0 + u];
  const float bias_o = bih[3 * HID + u0 + u] + bhh[3 * HID + u0 + u];

  float c_st = 0.f, h_prev = 0.f;

  float* odst = nullptr;
  if (obwd) odst = dir ? obwd : out;

  float4 xr[8];
  {
    const int t0 = dir ? (T_STEPS - 1) : 0;
    const float* xt = X + (size_t)t0 * BATCH * KDIM;
#pragma unroll
    for (int r = 0; r < 8; ++r) {
      int idx = tid + r * 512;
      xr[r] = *(const float4*)(xt + (size_t)(idx >> 7) * KDIM + (idx & 127) * 4);
    }
  }

  for (int s = 0; s < T_STEPS; ++s) {
    const int t = dir ? (T_STEPS - 1 - s) : s;
    const unsigned seqexp = epoch + (unsigned)s;

    // ---- convert prefetched x(t) -> LDS bf16 ----
#pragma unroll
    for (int r = 0; r < 8; ++r) {
      int idx = tid + r * 512;
      union { unsigned short u[4]; uint2 v; } p;
      p.u[0] = f2bf(xr[r].x); p.u[1] = f2bf(xr[r].y);
      p.u[2] = f2bf(xr[r].z); p.u[3] = f2bf(xr[r].w);
      *(uint2*)&xs[idx >> 7][(idx & 127) * 4] = p.v;
    }
    __syncthreads();   // B1

    // ---- x-projection MFMAs ----
    floatx4 acc0 = {0.f, 0.f, 0.f, 0.f}, acc1 = {0.f, 0.f, 0.f, 0.f};
    {
      const unsigned short* a0p = &xs[colx][kh * 256 + q * 8];
      const unsigned short* a1p = &xs[16 + colx][kh * 256 + q * 8];
#pragma unroll
      for (int ks = 0; ks < 8; ++ks) {
        short8 a0 = *(const short8*)(a0p + ks * 32);
        short8 a1 = *(const short8*)(a1p + ks * 32);
        acc0 = __builtin_amdgcn_mfma_f32_16x16x32_bf16(a0, bwx[ks], acc0, 0, 0, 0);
        acc1 = __builtin_amdgcn_mfma_f32_16x16x32_bf16(a1, bwx[ks], acc1, 0, 0, 0);
      }
    }

    // ---- issue x(t+1) prefetch ----
    {
      const int sn = (s + 1 < T_STEPS) ? (s + 1) : s;
      const int tn = dir ? (T_STEPS - 1 - sn) : sn;
      const float* xt = X + (size_t)tn * BATCH * KDIM;
#pragma unroll
      for (int r = 0; r < 8; ++r) {
        int idx = tid + r * 512;
        xr[r] = *(const float4*)(xt + (size_t)(idx >> 7) * KDIM + (idx & 127) * 4);
      }
    }

    const u64* hq = hwD + (s & 1) * 8192;

    // ---- sentinel: 256 threads cover all 256 columns (= all producers) ----
    if (tid < 256) {
      const u64* sp = hq + tid;         // row 0, column tid
      for (;;) {
        u64 sv = ldq<WG>(sp);
        if ((unsigned)(sv >> 32) == seqexp) break;
      }
    }
    __syncthreads();   // Bpoll

    // ---- bulk read + verify (retry for in-flight stragglers) ----
    u64 v[16];
    for (;;) {
      bulk16<WG>(hq + tid, v);
      unsigned bad = 0;
#pragma unroll
      for (int r = 0; r < 16; ++r) bad |= ((unsigned)(v[r] >> 32)) ^ seqexp;
      if (!bad) break;
      __builtin_amdgcn_s_sleep(1);
    }
    // ---- stage to LDS (dw0 already packed bf16 pair) ----
#pragma unroll
    for (int r = 0; r < 16; ++r) {
      int row = (tid >> 8) + 2 * r;
      *(unsigned*)&hs[row][(tid & 255) * 2] = (unsigned)v[r];
    }
    __syncthreads();   // B2

    // ---- h-projection MFMAs ----
    {
      const unsigned short* a0p = &hs[colx][kh * 256 + q * 8];
      const unsigned short* a1p = &hs[16 + colx][kh * 256 + q * 8];
#pragma unroll
      for (int ks = 0; ks < 8; ++ks) {
        short8 a0 = *(const short8*)(a0p + ks * 32);
        short8 a1 = *(const short8*)(a1p + ks * 32);
        acc0 = __builtin_amdgcn_mfma_f32_16x16x32_bf16(a0, bwh[ks], acc0, 0, 0, 0);
        acc1 = __builtin_amdgcn_mfma_f32_16x16x32_bf16(a1, bwh[ks], acc1, 0, 0, 0);
      }
    }
#pragma unroll
    for (int r = 0; r < 4; ++r) {
      gp[kh][q * 4 + r][nt * 16 + colx] = acc0[r];
      gp[kh][16 + q * 4 + r][nt * 16 + colx] = acc1[r];
    }
    __syncthreads();   // B3

    // ---- pointwise LSTM cell + zoneout ----
    float gi = gp[0][b][u]      + gp[1][b][u]      + bias_i;
    float gf = gp[0][b][16 + u] + gp[1][b][16 + u] + bias_f;
    float gg = gp[0][b][32 + u] + gp[1][b][32 + u] + bias_g;
    float go = gp[0][b][48 + u] + gp[1][b][48 + u] + bias_o;
    float si = fsigmoid(gi);
    float sf = fsigmoid(gf);
    float tg = ftanh(gg);
    float so = fsigmoid(go);
    float c_new = sf * c_st + si * tg;
    float h_new = so * ftanh(c_new);
    c_st = 0.9f * c_new + 0.1f * c_st;
    float h = 0.9f * h_new + 0.1f * h_prev;
    h_prev = h;

    // ---- publish: pair-pack qword {2 bf16 | seq32}, scoped store ----
    {
      unsigned myb = (unsigned)f2bf(h);
      unsigned pb = (unsigned)__shfl_xor((int)myb, 1);
      if (!(u & 1)) {
        u64 val = (((u64)(epoch + (unsigned)(s + 1))) << 32) |
                  (u64)(myb | (pb << 16));
        u64* hop = hwD + ((s + 1) & 1) * 8192 + ((b * HID + u0 + u) >> 1);
        stq<WG>(hop, val);
      }
    }

    // off the critical path: output write
    {
      size_t oidx = (size_t)(t * BATCH + b) * HID + u0 + u;
      if (odst) __builtin_nontemporal_store(h, &odst[oidx]);
      else atomicAdd(out + oidx, h);
    }
  }
}

// ---------------------------------------------------------------------------
// ctrl layout (u32): [0]=ctrFwd [1]=ctrBwd [2]=ctrPass [3]=claimed
// [4]=zeroFwd [5]=zeroBwd [6]=epoch [16..80)=slot_rec (0x100|xcd)
// ---------------------------------------------------------------------------
__global__ __launch_bounds__(512, 2) void lstm_persist(
    const float* __restrict__ X, const float* __restrict__ Wih,
    const float* __restrict__ Whh, const float* __restrict__ bih,
    const float* __restrict__ bhh, float* __restrict__ out,
    u64* __restrict__ hwq, float* __restrict__ obwd,
    unsigned* __restrict__ ctrl) {
  __shared__ unsigned short xs[32][520];
  __shared__ unsigned short hs[32][520];
  __shared__ float gp[2][32][64];
  __shared__ int meta[4];   // dir+1, slot, mode, epoch

  const int tid = threadIdx.x;

  if (tid == 0) {
    unsigned x;
    asm volatile("s_getreg_b32 %0, hwreg(HW_REG_XCC_ID)" : "=s"(x));
    const unsigned xcd = x & 15u;
    int dir = -1, slot = -1;
    if (xcd == 0u) {
      unsigned tk = __hip_atomic_fetch_add(&ctrl[0], 1u, __ATOMIC_RELAXED, __HIP_MEMORY_SCOPE_AGENT);
      if (tk < 32u) { dir = 0; slot = (int)tk; }
    } else if (xcd == 1u) {
      unsigned tk = __hip_atomic_fetch_add(&ctrl[1], 1u, __ATOMIC_RELAXED, __HIP_MEMORY_SCOPE_AGENT);
      if (tk < 32u) { dir = 1; slot = (int)tk; }
    }
    if (dir < 0) {
      unsigned p = __hip_atomic_fetch_add(&ctrl[2], 1u, __ATOMIC_RELAXED, __HIP_MEMORY_SCOPE_AGENT);
      if (p >= (unsigned)(NBLK - 96)) {   // last arrivals rescue-fill deficits
        unsigned tk = __hip_atomic_fetch_add(&ctrl[0], 1u, __ATOMIC_RELAXED, __HIP_MEMORY_SCOPE_AGENT);
        if (tk < 32u) { dir = 0; slot = (int)tk; }
        else {
          tk = __hip_atomic_fetch_add(&ctrl[1], 1u, __ATOMIC_RELAXED, __HIP_MEMORY_SCOPE_AGENT);
          if (tk < 32u) { dir = 1; slot = (int)tk; }
        }
      }
    }
    if (dir >= 0) {
      __hip_atomic_store(&ctrl[16 + dir * 32 + slot], 0x100u | xcd,
                         __ATOMIC_RELAXED, __HIP_MEMORY_SCOPE_AGENT);
      if (dir == 0 && slot == 0) {   // epoch broadcaster
        u64 rt;
        asm volatile("s_memrealtime %0\n\ts_waitcnt lgkmcnt(0)" : "=s"(rt));
        unsigned ep = ((unsigned)rt * 2654435761u) | 1u;
        __hip_atomic_store(&ctrl[6], ep, __ATOMIC_RELAXED, __HIP_MEMORY_SCOPE_AGENT);
      }
      __hip_atomic_fetch_add(&ctrl[3], 1u, __ATOMIC_RELAXED, __HIP_MEMORY_SCOPE_AGENT);
    }
    meta[0] = dir + 1;
    meta[1] = slot;
  }
  __syncthreads();
  const int dir = meta[0] - 1;
  if (dir < 0) return;             // non-claimed blocks exit, free the CU
  const int bsl = meta[1];

  if (tid == 0) {
    // wait for full roster (64 claimed blocks always co-residentable: no deadlock)
    while (__hip_atomic_load(&ctrl[3], __ATOMIC_RELAXED, __HIP_MEMORY_SCOPE_AGENT) < 64u)
      __builtin_amdgcn_s_sleep(1);
    unsigned ep;
    while ((ep = __hip_atomic_load(&ctrl[6], __ATOMIC_RELAXED, __HIP_MEMORY_SCOPE_AGENT)) == 0u)
      __builtin_amdgcn_s_sleep(1);
    // my direction XCD-uniform? (self-validating records, no fences needed)
    unsigned first = 0; int uni = 1;
    for (int i = 0; i < 32; ++i) {
      unsigned r;
      do {
        r = __hip_atomic_load(&ctrl[16 + dir * 32 + i], __ATOMIC_RELAXED, __HIP_MEMORY_SCOPE_AGENT);
      } while (!(r & 0x100u));
      if (i == 0) first = r; else uni &= (r == first);
    }
    meta[2] = uni;
    meta[3] = (int)ep;
  }
  __syncthreads();
  const int mode = meta[2];
  const unsigned epoch = (unsigned)meta[3];

  if (mode)
    run_loop<true>(X, Wih, Whh, bih, bhh, out, hwq, obwd, ctrl, dir, bsl, epoch, xs, hs, gp);
  else
    run_loop<false>(X, Wih, Whh, bih, bhh, out, hwq, obwd, ctrl, dir, bsl, epoch, xs, hs, gp);
}

// ---------------------------------------------------------------------------
extern "C" void kernel_launch(void* const* d_in, const int* in_sizes, int n_in,
                              void* d_out, int out_size, void* d_ws, size_t ws_size,
                              hipStream_t stream) {
  const float* X   = (const float*)d_in[0];
  const float* Wih = (const float*)d_in[1];
  const float* Whh = (const float*)d_in[2];
  const float* bih = (const float*)d_in[3];
  const float* bhh = (const float*)d_in[4];
  float* out = (float*)d_out;

  // workspace layout:
  //   [0, 256KB):        hwq = [2 dir][2 buf][32][256] qwords {2bf16|seq32}
  //   [256KB, +512B):    ctrl (claim/rendezvous)
  //   [1MB, 65MB):       bwd-direction output buffer (split-store mode)
  u64* hwq = (u64*)d_ws;                               // 32768 qwords
  unsigned* ctrl = (unsigned*)((char*)d_ws + (256u << 10));

  const size_t OB_OFF = (size_t)1 << 20;
  const size_t OB_BYTES = (size_t)T_STEPS * BATCH * HID * sizeof(float); // 64MB

  float* obwd = nullptr;
  if (ws_size >= OB_OFF + OB_BYTES)
    obwd = (float*)((char*)d_ws + OB_OFF);

  if (!obwd)
    hipMemsetAsync(d_out, 0, (size_t)out_size * sizeof(float), stream);

  hipLaunchKernelGGL(init_kernel, dim3(1), dim3(128), 0, stream, ctrl);
  hipLaunchKernelGGL(lstm_persist, dim3(NBLK), dim3(512), 0, stream,
                     X, Wih, Whh, bih, bhh, out, hwq, obwd, ctrl);
  if (obwd)
    hipLaunchKernelGGL(merge_kernel, dim3(2048), dim3(256), 0, stream,
                       out, obwd, (T_STEPS * BATCH * HID) / 4);
}

// Round 7
// 3896.362 us; speedup vs baseline: 1.2084x; 1.0881x over previous
//
#include <hip/hip_runtime.h>

#define T_STEPS 1024
#define BATCH 32
#define HID 512
#define GATES 2048   // 4*HID
#define KDIM 512     // input size == HID

typedef __attribute__((ext_vector_type(8))) short short8;
typedef __attribute__((ext_vector_type(4))) float floatx4;

__device__ __forceinline__ unsigned short f2bf(float f) {
  union { float f; unsigned u; } v; v.f = f;
  return (unsigned short)((v.u + 0x7FFFu + ((v.u >> 16) & 1u)) >> 16);
}
__device__ __forceinline__ float fsigmoid(float x) {
  return 1.0f / (1.0f + __expf(-x));
}
__device__ __forceinline__ float ftanh(float x) {
  return 2.0f / (1.0f + __expf(-2.0f * x)) - 1.0f;
}

// ---------------------------------------------------------------------------
// init: zero the (h|seq) dword ping-pong buffers with agent-scope stores so
// the persistent kernel's sc1 polls never see stale poison.
// Zero == (h=0 | seq=0), which is exactly what step-0 consumers poll for.
// ---------------------------------------------------------------------------
__global__ void init_kernel(unsigned* __restrict__ hbuf_u) {  // 65536 dwords
  int idx = blockIdx.x * 256 + threadIdx.x;     // 65536 threads
  __hip_atomic_store(&hbuf_u[idx], 0u, __ATOMIC_RELAXED, __HIP_MEMORY_SCOPE_AGENT);
}

// ---------------------------------------------------------------------------
// add bwd-direction buffer into out (split-store mode only)
// ---------------------------------------------------------------------------
__global__ void merge_kernel(float* __restrict__ out,
                             const float* __restrict__ add, int n4) {
  int i = blockIdx.x * 256 + threadIdx.x;
  int stride = gridDim.x * 256;
  for (; i < n4; i += stride) {
    float4 a = ((const float4*)add)[i];
    float4 o = ((float4*)out)[i];
    o.x += a.x; o.y += a.y; o.z += a.z; o.w += a.w;
    ((float4*)out)[i] = o;
  }
}

// ---------------------------------------------------------------------------
// Persistent bidirectional zoneout-LSTM. 64 blocks x 512 thr.
// blocks 0..31: forward, 32..63: backward. Block owns 16 hidden units
// (64 gate cols). W_hh / W_ih fragments live in registers.
//
// h-exchange protocol (flagless, self-validating, cheap-sentinel — as R4):
//  - h dwords (bf16 h | step_seq<<16), seq = s+1, agent-scope relaxed.
//  - consumer: pre-issue r=1..15, spin on the r=0 sentinel qword (whole
//    per-thread region belongs to ONE producer), verify embedded seqs,
//    rare retry. seq unique per step -> no ABA; ping-pong x2 safe.
//
// Critical-path discipline (R6 theory, unbundled here): vmcnt retires IN
// ORDER, so the sentinel wait drains EVERYTHING older in the vmem queue.
// Therefore: (1) the 64 KB x(t+1) prefetch is issued AFTER the poll (it
// hides under stage/h-MFMA/pointwise/publish and is waited at next step's
// convert with vmcnt(2), NOT draining the younger publish/out acks);
// (2) the out-store is a plain cached store (L2 ack), not nontemporal
// (suspected memory-ack in the drain chain all prior rounds).
// ---------------------------------------------------------------------------
__global__ __launch_bounds__(512) void lstm_persist(
    const float* __restrict__ X,           // [1024, 32, 512]
    const float* __restrict__ Wih,         // [2048, 512]
    const float* __restrict__ Whh,         // [2048, 512]
    const float* __restrict__ bih,         // [2048]
    const float* __restrict__ bhh,         // [2048]
    float* __restrict__ out,               // [1024*32*512]
    unsigned* __restrict__ hw,             // [2][2][32][512] dwords (h|seq)
    float* __restrict__ obwd) {            // bwd out buffer (split) or null
  __shared__ unsigned short xs[32][520];   // staged x(t) bf16, +8 pad
  __shared__ unsigned short hs[32][520];   // staged h(s-1) bf16, +8 pad
  __shared__ float gp[2][32][64];          // gate partials per k-half

  const int tid = threadIdx.x;
  const int bid = blockIdx.x;
  const int dir = bid >> 5;
  const int bsl = bid & 31;
  const int u0 = bsl * 16;

  unsigned* hwD = hw + dir * 2 * (BATCH * HID);   // per-direction dword region

  const int w = tid >> 6, lane = tid & 63;
  const int kh = w >> 2;   // k-half: [kh*256, kh*256+256)
  const int nt = w & 3;    // gate index (16-col n-tile)
  const int colx = lane & 15, q = lane >> 4;

  // Preload this wave's B-fragments into registers: gate nt, unit u0+colx.
  short8 bwh[8], bwx[8];
  {
    const size_t roff = (size_t)(nt * HID + u0 + colx) * KDIM + kh * 256 + q * 8;
    const float* wrh = Whh + roff;
    const float* wrx = Wih + roff;
#pragma unroll
    for (int ks = 0; ks < 8; ++ks) {
      float4 h0 = *(const float4*)(wrh + ks * 32);
      float4 h1 = *(const float4*)(wrh + ks * 32 + 4);
      union { unsigned short u[8]; short8 v; } pk;
      pk.u[0] = f2bf(h0.x); pk.u[1] = f2bf(h0.y); pk.u[2] = f2bf(h0.z); pk.u[3] = f2bf(h0.w);
      pk.u[4] = f2bf(h1.x); pk.u[5] = f2bf(h1.y); pk.u[6] = f2bf(h1.z); pk.u[7] = f2bf(h1.w);
      bwh[ks] = pk.v;
      float4 x0 = *(const float4*)(wrx + ks * 32);
      float4 x1 = *(const float4*)(wrx + ks * 32 + 4);
      union { unsigned short u[8]; short8 v; } px;
      px.u[0] = f2bf(x0.x); px.u[1] = f2bf(x0.y); px.u[2] = f2bf(x0.z); px.u[3] = f2bf(x0.w);
      px.u[4] = f2bf(x1.x); px.u[5] = f2bf(x1.y); px.u[6] = f2bf(x1.z); px.u[7] = f2bf(x1.w);
      bwx[ks] = px.v;
    }
  }

  // Per-thread pointwise assignment: batch b, unit u (global col u0+u)
  const int b = tid >> 4, u = tid & 15;
  const float bias_i = bih[0 * HID + u0 + u] + bhh[0 * HID + u0 + u];
  const float bias_f = bih[1 * HID + u0 + u] + bhh[1 * HID + u0 + u];
  const float bias_g = bih[2 * HID + u0 + u] + bhh[2 * HID + u0 + u];
  const float bias_o = bih[3 * HID + u0 + u] + bhh[3 * HID + u0 + u];

  float c_st = 0.f, h_prev = 0.f;

  float* odst = nullptr;
  if (obwd) odst = dir ? obwd : out;   // split-store mode

  // ---- prologue: prefetch x(t0) into registers ----
  float4 xr[8];
  {
    const int t0 = dir ? (T_STEPS - 1) : 0;
    const float* xt = X + (size_t)t0 * BATCH * KDIM;
#pragma unroll
    for (int r = 0; r < 8; ++r) {
      int idx = tid + r * 512;
      xr[r] = *(const float4*)(xt + (size_t)(idx >> 7) * KDIM + (idx & 127) * 4);
    }
  }

  for (int s = 0; s < T_STEPS; ++s) {
    const int t = dir ? (T_STEPS - 1 - s) : s;

    // ---- convert prefetched x(t) -> LDS bf16 ----
    // (compiler waits vmcnt(2) here: xr loads done, publish/out acks NOT
    //  drained — they are younger than the youngest xr load)
#pragma unroll
    for (int r = 0; r < 8; ++r) {
      int idx = tid + r * 512;
      union { unsigned short u[4]; uint2 v; } p;
      p.u[0] = f2bf(xr[r].x); p.u[1] = f2bf(xr[r].y);
      p.u[2] = f2bf(xr[r].z); p.u[3] = f2bf(xr[r].w);
      *(uint2*)&xs[idx >> 7][(idx & 127) * 4] = p.v;
    }
    __syncthreads();   // B1

    // ---- x-projection MFMAs (independent of h) ----
    floatx4 acc0 = {0.f, 0.f, 0.f, 0.f}, acc1 = {0.f, 0.f, 0.f, 0.f};
    {
      const unsigned short* a0p = &xs[colx][kh * 256 + q * 8];
      const unsigned short* a1p = &xs[16 + colx][kh * 256 + q * 8];
#pragma unroll
      for (int ks = 0; ks < 8; ++ks) {
        short8 a0 = *(const short8*)(a0p + ks * 32);
        short8 a1 = *(const short8*)(a1p + ks * 32);
        acc0 = __builtin_amdgcn_mfma_f32_16x16x32_bf16(a0, bwx[ks], acc0, 0, 0, 0);
        acc1 = __builtin_amdgcn_mfma_f32_16x16x32_bf16(a1, bwx[ks], acc1, 0, 0, 0);
      }
    }

    // ---- wait + stage: cheap-sentinel poll, then verified bulk read ----
    // vmem queue entering the spin: only the (small, L2/LLC) publish ack +
    // cached out-store ack from step s-1 — the cheap drain.
    {
      const unsigned long long* hq =
          (const unsigned long long*)(hwD + (s & 1) * (BATCH * HID));
      const unsigned long long rep = ((unsigned long long)(unsigned)s << 16) |
                                     ((unsigned long long)(unsigned)s << 48);
      const unsigned long long msk = 0xFFFF0000FFFF0000ULL;
      unsigned long long v[16];

      // pre-issue bulk loads r=1..15 (fly during the sentinel spin)
#pragma unroll
      for (int r = 1; r < 16; ++r)
        v[r] = __hip_atomic_load(&hq[tid + r * 512], __ATOMIC_RELAXED,
                                 __HIP_MEMORY_SCOPE_AGENT);
      // sentinel spin: 8 B/thread/iter; whole region is ONE producer.
      for (;;) {
        v[0] = __hip_atomic_load(&hq[tid], __ATOMIC_RELAXED,
                                 __HIP_MEMORY_SCOPE_AGENT);
        if (!((v[0] ^ rep) & msk)) break;
      }
      // verify pre-issued loads; rare retry if store burst was mid-flight
      for (;;) {
        unsigned long long bad = 0;
#pragma unroll
        for (int r = 1; r < 16; ++r) bad |= (v[r] ^ rep);
        if (!(bad & msk)) break;
        __builtin_amdgcn_s_sleep(1);
#pragma unroll
        for (int r = 1; r < 16; ++r)
          v[r] = __hip_atomic_load(&hq[tid + r * 512], __ATOMIC_RELAXED,
                                   __HIP_MEMORY_SCOPE_AGENT);
      }

      // ---- NOW issue x(t+1) prefetch: hides under stage/h-MFMA/pointwise/
      //      publish; waited at next convert (vmcnt(2), cheap).
      {
        const int sn = (s + 1 < T_STEPS) ? (s + 1) : s;
        const int tn = dir ? (T_STEPS - 1 - sn) : sn;
        const float* xt = X + (size_t)tn * BATCH * KDIM;
#pragma unroll
        for (int r = 0; r < 8; ++r) {
          int idx = tid + r * 512;
          xr[r] = *(const float4*)(xt + (size_t)(idx >> 7) * KDIM + (idx & 127) * 4);
        }
      }

      // ---- stage h(s-1) -> LDS ----
#pragma unroll
      for (int r = 0; r < 16; ++r) {
        int g = tid + r * 512;                       // qword index 0..8191
        unsigned packed = (unsigned)(v[r] & 0xFFFFu) |
                          ((unsigned)(v[r] >> 32) << 16);
        *(unsigned*)&hs[g >> 8][(g & 255) * 2] = packed;
      }
    }
    __syncthreads();   // B2 (stage complete before h-MFMA reads)

    // ---- h-projection MFMAs ----
    {
      const unsigned short* a0p = &hs[colx][kh * 256 + q * 8];
      const unsigned short* a1p = &hs[16 + colx][kh * 256 + q * 8];
#pragma unroll
      for (int ks = 0; ks < 8; ++ks) {
        short8 a0 = *(const short8*)(a0p + ks * 32);
        short8 a1 = *(const short8*)(a1p + ks * 32);
        acc0 = __builtin_amdgcn_mfma_f32_16x16x32_bf16(a0, bwh[ks], acc0, 0, 0, 0);
        acc1 = __builtin_amdgcn_mfma_f32_16x16x32_bf16(a1, bwh[ks], acc1, 0, 0, 0);
      }
    }
#pragma unroll
    for (int r = 0; r < 4; ++r) {
      gp[kh][q * 4 + r][nt * 16 + colx] = acc0[r];
      gp[kh][16 + q * 4 + r][nt * 16 + colx] = acc1[r];
    }
    __syncthreads();   // B3

    // ---- pointwise LSTM cell + zoneout for (b, u) ----
    float gi = gp[0][b][u]      + gp[1][b][u]      + bias_i;
    float gf = gp[0][b][16 + u] + gp[1][b][16 + u] + bias_f;
    float gg = gp[0][b][32 + u] + gp[1][b][32 + u] + bias_g;
    float go = gp[0][b][48 + u] + gp[1][b][48 + u] + bias_o;
    float si = fsigmoid(gi);
    float sf = fsigmoid(gf);
    float tg = ftanh(gg);
    float so = fsigmoid(go);
    float c_new = sf * c_st + si * tg;
    float h_new = so * ftanh(c_new);
    c_st = 0.9f * c_new + 0.1f * c_st;
    float h = 0.9f * h_new + 0.1f * h_prev;
    h_prev = h;

    // ---- publish h: per-thread (h|seq) dword, sc1; no barrier, no flag ----
    {
      unsigned D = (unsigned)f2bf(h) | ((unsigned)(s + 1) << 16);
      unsigned* hop = hwD + ((s + 1) & 1) * (BATCH * HID);
      __hip_atomic_store(&hop[b * HID + u0 + u], D,
                         __ATOMIC_RELAXED, __HIP_MEMORY_SCOPE_AGENT);
    }

    // off the critical path: output write (plain cached store: L2 ack only)
    {
      size_t oidx = (size_t)(t * BATCH + b) * HID + u0 + u;
      if (odst) odst[oidx] = h;
      else atomicAdd(out + oidx, h);   // fallback: tiny workspace
    }
  }
}

// ---------------------------------------------------------------------------
extern "C" void kernel_launch(void* const* d_in, const int* in_sizes, int n_in,
                              void* d_out, int out_size, void* d_ws, size_t ws_size,
                              hipStream_t stream) {
  const float* X   = (const float*)d_in[0];
  const float* Wih = (const float*)d_in[1];
  const float* Whh = (const float*)d_in[2];
  const float* bih = (const float*)d_in[3];
  const float* bhh = (const float*)d_in[4];
  float* out = (float*)d_out;

  // workspace layout:
  //   [0, 256KB):      hw = [2 dir][2 buf][32][512] (h|seq) dwords (256 KB)
  //   [1MB, 65MB):     bwd-direction output buffer (split-store mode)
  unsigned* hw = (unsigned*)d_ws;                     // 65536 dwords

  const size_t OB_OFF = (size_t)1 << 20;
  const size_t OB_BYTES = (size_t)T_STEPS * BATCH * HID * sizeof(float); // 64MB

  float* obwd = nullptr;
  if (ws_size >= OB_OFF + OB_BYTES)
    obwd = (float*)((char*)d_ws + OB_OFF);

  if (!obwd)   // fallback: atomicAdd accumulation needs zeroed out
    hipMemsetAsync(d_out, 0, (size_t)out_size * sizeof(float), stream);

  hipLaunchKernelGGL(init_kernel, dim3(256), dim3(256), 0, stream, hw);
  hipLaunchKernelGGL(lstm_persist, dim3(64), dim3(512), 0, stream,
                     X, Wih, Whh, bih, bhh, out, hw, obwd);
  if (obwd)
    hipLaunchKernelGGL(merge_kernel, dim3(2048), dim3(256), 0, stream,
                       out, obwd, (T_STEPS * BATCH * HID) / 4);
}

// Round 8
// 3784.546 us; speedup vs baseline: 1.2441x; 1.0295x over previous
//
#include <hip/hip_runtime.h>

#define T_STEPS 1024
#define BATCH 32
#define HID 512
#define GATES 2048   // 4*HID
#define KDIM 512     // input size == HID

typedef __attribute__((ext_vector_type(8))) short short8;
typedef __attribute__((ext_vector_type(4))) float floatx4;

__device__ __forceinline__ unsigned short f2bf(float f) {
  union { float f; unsigned u; } v; v.f = f;
  return (unsigned short)((v.u + 0x7FFFu + ((v.u >> 16) & 1u)) >> 16);
}
__device__ __forceinline__ float fsigmoid(float x) {
  return 1.0f / (1.0f + __expf(-x));
}
__device__ __forceinline__ float ftanh(float x) {
  return 2.0f / (1.0f + __expf(-2.0f * x)) - 1.0f;
}

// ---------------------------------------------------------------------------
// init: zero the (h|seq) dword ping-pong buffers with agent-scope stores so
// the persistent kernel's sc1 polls never see stale poison.
// Zero == (h=0 | seq=0), which is exactly what step-0 consumers poll for.
// ---------------------------------------------------------------------------
__global__ void init_kernel(unsigned* __restrict__ hbuf_u) {  // 65536 dwords
  int idx = blockIdx.x * 256 + threadIdx.x;     // 65536 threads
  __hip_atomic_store(&hbuf_u[idx], 0u, __ATOMIC_RELAXED, __HIP_MEMORY_SCOPE_AGENT);
}

// ---------------------------------------------------------------------------
// add bwd-direction buffer into out (split-store mode only)
// ---------------------------------------------------------------------------
__global__ void merge_kernel(float* __restrict__ out,
                             const float* __restrict__ add, int n4) {
  int i = blockIdx.x * 256 + threadIdx.x;
  int stride = gridDim.x * 256;
  for (; i < n4; i += stride) {
    float4 a = ((const float4*)add)[i];
    float4 o = ((float4*)out)[i];
    o.x += a.x; o.y += a.y; o.z += a.z; o.w += a.w;
    ((float4*)out)[i] = o;
  }
}

// ---------------------------------------------------------------------------
// Persistent bidirectional zoneout-LSTM. 64 blocks x 512 thr.
// blocks 0..31: forward, 32..63: backward. Block owns 16 hidden units
// (64 gate cols). W_hh / W_ih fragments live in registers.
//
// h-exchange protocol (flagless, self-validating, EARLY-BURST poll):
//  - h dwords (bf16 h | step_seq<<16), seq = s+1, agent-scope relaxed.
//  - consumer at step s: issue ALL 16 poll qword loads right after B1,
//    BEFORE the x-MFMA phase. The burst flies during x-MFMA and samples
//    the LLC ~RT after issue — by which time producers' publishes (one-way
//    ~400cy, made ~400cy earlier) have landed. First check after x-MFMA is
//    fresh in steady state -> discovery + verify collapse to ZERO extra RT.
//    Stale case: tight reload-all loop (1 RT/iter, no sleep).
//  - seq unique per step -> no ABA (torn 8B reads detected per-dword);
//    ping-pong x2 overwrite-safe by construction.
//
// Critical-path discipline (R7, kept): vmcnt retires IN ORDER, so the
// x(t+1) prefetch is issued AFTER the poll (hides under stage/h-MFMA/
// pointwise/publish; waited at next convert); out-store is a plain cached
// store (L2 ack), not nontemporal.
// ---------------------------------------------------------------------------
__global__ __launch_bounds__(512) void lstm_persist(
    const float* __restrict__ X,           // [1024, 32, 512]
    const float* __restrict__ Wih,         // [2048, 512]
    const float* __restrict__ Whh,         // [2048, 512]
    const float* __restrict__ bih,         // [2048]
    const float* __restrict__ bhh,         // [2048]
    float* __restrict__ out,               // [1024*32*512]
    unsigned* __restrict__ hw,             // [2][2][32][512] dwords (h|seq)
    float* __restrict__ obwd) {            // bwd out buffer (split) or null
  __shared__ unsigned short xs[32][520];   // staged x(t) bf16, +8 pad
  __shared__ unsigned short hs[32][520];   // staged h(s-1) bf16, +8 pad
  __shared__ float gp[2][32][64];          // gate partials per k-half

  const int tid = threadIdx.x;
  const int bid = blockIdx.x;
  const int dir = bid >> 5;
  const int bsl = bid & 31;
  const int u0 = bsl * 16;

  unsigned* hwD = hw + dir * 2 * (BATCH * HID);   // per-direction dword region

  const int w = tid >> 6, lane = tid & 63;
  const int kh = w >> 2;   // k-half: [kh*256, kh*256+256)
  const int nt = w & 3;    // gate index (16-col n-tile)
  const int colx = lane & 15, q = lane >> 4;

  // Preload this wave's B-fragments into registers: gate nt, unit u0+colx.
  short8 bwh[8], bwx[8];
  {
    const size_t roff = (size_t)(nt * HID + u0 + colx) * KDIM + kh * 256 + q * 8;
    const float* wrh = Whh + roff;
    const float* wrx = Wih + roff;
#pragma unroll
    for (int ks = 0; ks < 8; ++ks) {
      float4 h0 = *(const float4*)(wrh + ks * 32);
      float4 h1 = *(const float4*)(wrh + ks * 32 + 4);
      union { unsigned short u[8]; short8 v; } pk;
      pk.u[0] = f2bf(h0.x); pk.u[1] = f2bf(h0.y); pk.u[2] = f2bf(h0.z); pk.u[3] = f2bf(h0.w);
      pk.u[4] = f2bf(h1.x); pk.u[5] = f2bf(h1.y); pk.u[6] = f2bf(h1.z); pk.u[7] = f2bf(h1.w);
      bwh[ks] = pk.v;
      float4 x0 = *(const float4*)(wrx + ks * 32);
      float4 x1 = *(const float4*)(wrx + ks * 32 + 4);
      union { unsigned short u[8]; short8 v; } px;
      px.u[0] = f2bf(x0.x); px.u[1] = f2bf(x0.y); px.u[2] = f2bf(x0.z); px.u[3] = f2bf(x0.w);
      px.u[4] = f2bf(x1.x); px.u[5] = f2bf(x1.y); px.u[6] = f2bf(x1.z); px.u[7] = f2bf(x1.w);
      bwx[ks] = px.v;
    }
  }

  // Per-thread pointwise assignment: batch b, unit u (global col u0+u)
  const int b = tid >> 4, u = tid & 15;
  const float bias_i = bih[0 * HID + u0 + u] + bhh[0 * HID + u0 + u];
  const float bias_f = bih[1 * HID + u0 + u] + bhh[1 * HID + u0 + u];
  const float bias_g = bih[2 * HID + u0 + u] + bhh[2 * HID + u0 + u];
  const float bias_o = bih[3 * HID + u0 + u] + bhh[3 * HID + u0 + u];

  float c_st = 0.f, h_prev = 0.f;

  float* odst = nullptr;
  if (obwd) odst = dir ? obwd : out;   // split-store mode

  // ---- prologue: prefetch x(t0) into registers ----
  float4 xr[8];
  {
    const int t0 = dir ? (T_STEPS - 1) : 0;
    const float* xt = X + (size_t)t0 * BATCH * KDIM;
#pragma unroll
    for (int r = 0; r < 8; ++r) {
      int idx = tid + r * 512;
      xr[r] = *(const float4*)(xt + (size_t)(idx >> 7) * KDIM + (idx & 127) * 4);
    }
  }

  for (int s = 0; s < T_STEPS; ++s) {
    const int t = dir ? (T_STEPS - 1 - s) : s;

    // ---- convert prefetched x(t) -> LDS bf16 ----
    // (natural vmcnt wait here covers the x-prefetch AND retires any
    //  leftover acks — the vmem queue is empty after this)
#pragma unroll
    for (int r = 0; r < 8; ++r) {
      int idx = tid + r * 512;
      union { unsigned short u[4]; uint2 v; } p;
      p.u[0] = f2bf(xr[r].x); p.u[1] = f2bf(xr[r].y);
      p.u[2] = f2bf(xr[r].z); p.u[3] = f2bf(xr[r].w);
      *(uint2*)&xs[idx >> 7][(idx & 127) * 4] = p.v;
    }
    __syncthreads();   // B1

    // ---- issue the h(s-1) poll burst EARLY: flies under x-MFMA ----
    const unsigned long long* hq =
        (const unsigned long long*)(hwD + (s & 1) * (BATCH * HID));
    const unsigned long long rep = ((unsigned long long)(unsigned)s << 16) |
                                   ((unsigned long long)(unsigned)s << 48);
    const unsigned long long msk = 0xFFFF0000FFFF0000ULL;
    unsigned long long v[16];
#pragma unroll
    for (int r = 0; r < 16; ++r)
      v[r] = __hip_atomic_load(&hq[tid + r * 512], __ATOMIC_RELAXED,
                               __HIP_MEMORY_SCOPE_AGENT);

    // ---- x-projection MFMAs (LDS-only; poll burst in flight) ----
    floatx4 acc0 = {0.f, 0.f, 0.f, 0.f}, acc1 = {0.f, 0.f, 0.f, 0.f};
    {
      const unsigned short* a0p = &xs[colx][kh * 256 + q * 8];
      const unsigned short* a1p = &xs[16 + colx][kh * 256 + q * 8];
#pragma unroll
      for (int ks = 0; ks < 8; ++ks) {
        short8 a0 = *(const short8*)(a0p + ks * 32);
        short8 a1 = *(const short8*)(a1p + ks * 32);
        acc0 = __builtin_amdgcn_mfma_f32_16x16x32_bf16(a0, bwx[ks], acc0, 0, 0, 0);
        acc1 = __builtin_amdgcn_mfma_f32_16x16x32_bf16(a1, bwx[ks], acc1, 0, 0, 0);
      }
    }

    // ---- check burst (steady state: fresh on first check, zero extra RT);
    //      stale: tight reload-all loop, 1 RT per iteration ----
    for (;;) {
      unsigned long long bad = 0;
#pragma unroll
      for (int r = 0; r < 16; ++r) bad |= (v[r] ^ rep);
      if (!(bad & msk)) break;
#pragma unroll
      for (int r = 0; r < 16; ++r)
        v[r] = __hip_atomic_load(&hq[tid + r * 512], __ATOMIC_RELAXED,
                                 __HIP_MEMORY_SCOPE_AGENT);
    }

    // ---- NOW issue x(t+1) prefetch: hides under stage/h-MFMA/pointwise/
    //      publish; waited at next convert.
    {
      const int sn = (s + 1 < T_STEPS) ? (s + 1) : s;
      const int tn = dir ? (T_STEPS - 1 - sn) : sn;
      const float* xt = X + (size_t)tn * BATCH * KDIM;
#pragma unroll
      for (int r = 0; r < 8; ++r) {
        int idx = tid + r * 512;
        xr[r] = *(const float4*)(xt + (size_t)(idx >> 7) * KDIM + (idx & 127) * 4);
      }
    }

    // ---- stage h(s-1) -> LDS ----
#pragma unroll
    for (int r = 0; r < 16; ++r) {
      int g = tid + r * 512;                       // qword index 0..8191
      unsigned packed = (unsigned)(v[r] & 0xFFFFu) |
                        ((unsigned)(v[r] >> 32) << 16);
      *(unsigned*)&hs[g >> 8][(g & 255) * 2] = packed;
    }
    __syncthreads();   // B2 (stage complete before h-MFMA reads)

    // ---- h-projection MFMAs ----
    {
      const unsigned short* a0p = &hs[colx][kh * 256 + q * 8];
      const unsigned short* a1p = &hs[16 + colx][kh * 256 + q * 8];
#pragma unroll
      for (int ks = 0; ks < 8; ++ks) {
        short8 a0 = *(const short8*)(a0p + ks * 32);
        short8 a1 = *(const short8*)(a1p + ks * 32);
        acc0 = __builtin_amdgcn_mfma_f32_16x16x32_bf16(a0, bwh[ks], acc0, 0, 0, 0);
        acc1 = __builtin_amdgcn_mfma_f32_16x16x32_bf16(a1, bwh[ks], acc1, 0, 0, 0);
      }
    }
#pragma unroll
    for (int r = 0; r < 4; ++r) {
      gp[kh][q * 4 + r][nt * 16 + colx] = acc0[r];
      gp[kh][16 + q * 4 + r][nt * 16 + colx] = acc1[r];
    }
    __syncthreads();   // B3

    // ---- pointwise LSTM cell + zoneout for (b, u) ----
    float gi = gp[0][b][u]      + gp[1][b][u]      + bias_i;
    float gf = gp[0][b][16 + u] + gp[1][b][16 + u] + bias_f;
    float gg = gp[0][b][32 + u] + gp[1][b][32 + u] + bias_g;
    float go = gp[0][b][48 + u] + gp[1][b][48 + u] + bias_o;
    float si = fsigmoid(gi);
    float sf = fsigmoid(gf);
    float tg = ftanh(gg);
    float so = fsigmoid(go);
    float c_new = sf * c_st + si * tg;
    float h_new = so * ftanh(c_new);
    c_st = 0.9f * c_new + 0.1f * c_st;
    float h = 0.9f * h_new + 0.1f * h_prev;
    h_prev = h;

    // ---- publish h: per-thread (h|seq) dword, sc1; no barrier, no flag ----
    {
      unsigned D = (unsigned)f2bf(h) | ((unsigned)(s + 1) << 16);
      unsigned* hop = hwD + ((s + 1) & 1) * (BATCH * HID);
      __hip_atomic_store(&hop[b * HID + u0 + u], D,
                         __ATOMIC_RELAXED, __HIP_MEMORY_SCOPE_AGENT);
    }

    // off the critical path: output write (plain cached store: L2 ack only)
    {
      size_t oidx = (size_t)(t * BATCH + b) * HID + u0 + u;
      if (odst) odst[oidx] = h;
      else atomicAdd(out + oidx, h);   // fallback: tiny workspace
    }
  }
}

// ---------------------------------------------------------------------------
extern "C" void kernel_launch(void* const* d_in, const int* in_sizes, int n_in,
                              void* d_out, int out_size, void* d_ws, size_t ws_size,
                              hipStream_t stream) {
  const float* X   = (const float*)d_in[0];
  const float* Wih = (const float*)d_in[1];
  const float* Whh = (const float*)d_in[2];
  const float* bih = (const float*)d_in[3];
  const float* bhh = (const float*)d_in[4];
  float* out = (float*)d_out;

  // workspace layout:
  //   [0, 256KB):      hw = [2 dir][2 buf][32][512] (h|seq) dwords (256 KB)
  //   [1MB, 65MB):     bwd-direction output buffer (split-store mode)
  unsigned* hw = (unsigned*)d_ws;                     // 65536 dwords

  const size_t OB_OFF = (size_t)1 << 20;
  const size_t OB_BYTES = (size_t)T_STEPS * BATCH * HID * sizeof(float); // 64MB

  float* obwd = nullptr;
  if (ws_size >= OB_OFF + OB_BYTES)
    obwd = (float*)((char*)d_ws + OB_OFF);

  if (!obwd)   // fallback: atomicAdd accumulation needs zeroed out
    hipMemsetAsync(d_out, 0, (size_t)out_size * sizeof(float), stream);

  hipLaunchKernelGGL(init_kernel, dim3(256), dim3(256), 0, stream, hw);
  hipLaunchKernelGGL(lstm_persist, dim3(64), dim3(512), 0, stream,
                     X, Wih, Whh, bih, bhh, out, hw, obwd);
  if (obwd)
    hipLaunchKernelGGL(merge_kernel, dim3(2048), dim3(256), 0, stream,
                       out, obwd, (T_STEPS * BATCH * HID) / 4);
}

// Round 10
// 3176.183 us; speedup vs baseline: 1.4823x; 1.1915x over previous
//
#include <hip/hip_runtime.h>

#define T_STEPS 1024
#define BATCH 32
#define HID 512
#define KDIM 512     // input size == HID

typedef __attribute__((ext_vector_type(8))) short short8;
typedef __attribute__((ext_vector_type(4))) float floatx4;
typedef __attribute__((ext_vector_type(4))) int int4v;

__device__ __forceinline__ unsigned short f2bf(float f) {
  union { float f; unsigned u; } v; v.f = f;
  return (unsigned short)((v.u + 0x7FFFu + ((v.u >> 16) & 1u)) >> 16);
}
__device__ __forceinline__ float fsigmoid(float x) {
  return 1.0f / (1.0f + __expf(-x));
}
__device__ __forceinline__ float ftanh(float x) {
  return 2.0f / (1.0f + __expf(-2.0f * x)) - 1.0f;
}
__device__ __forceinline__ void waitv0() {
  asm volatile("s_waitcnt vmcnt(0)" ::: "memory");
}

// issue 8 coalesced 16B exchange reads (sc0 sc1: bypass L1+L2, read at LLC —
// required for cross-XCD visibility). Loads are left IN FLIGHT: caller must
// waitv0() + sched_barrier(0) before reading v[] (rule #18).
__device__ __forceinline__ void issue_burst(const unsigned* base, int tid,
                                            int4v v[8]) {
#pragma unroll
  for (int g = 0; g < 8; ++g) {
    const unsigned* p = base + 4 * (tid + g * 512);
    asm volatile("global_load_dwordx4 %0, %1, off sc0 sc1"
                 : "=&v"(v[g]) : "v"(p) : "memory");
  }
}

// ---------------------------------------------------------------------------
// init: zero the (h|seq) dword ping-pong buffers with agent-scope stores so
// the persistent kernel's sc1 polls never see stale poison.
// Zero == (h=0 | seq=0), which is exactly what step-0 consumers poll for.
// ---------------------------------------------------------------------------
__global__ void init_kernel(unsigned* __restrict__ hbuf_u) {  // 65536 dwords
  int idx = blockIdx.x * 256 + threadIdx.x;
  __hip_atomic_store(&hbuf_u[idx], 0u, __ATOMIC_RELAXED, __HIP_MEMORY_SCOPE_AGENT);
}

__global__ void merge_kernel(float* __restrict__ out,
                             const float* __restrict__ add, int n4) {
  int i = blockIdx.x * 256 + threadIdx.x;
  int stride = gridDim.x * 256;
  for (; i < n4; i += stride) {
    float4 a = ((const float4*)add)[i];
    float4 o = ((float4*)out)[i];
    o.x += a.x; o.y += a.y; o.z += a.z; o.w += a.w;
    ((float4*)out)[i] = o;
  }
}

// ---------------------------------------------------------------------------
// Persistent bidirectional zoneout-LSTM. 64 blocks x 512 thr.
// blocks 0..31: forward, 32..63: backward. Block owns 16 hidden units.
//
// NEW wave decomposition (kills the gp/LDS transpose + barrier B3 + its
// 4-way bank conflicts): wave w = (mh = w>>2 batch-half, ug = w&3 unit-group
// of 4 units). MFMA col c = unit_local(c>>2)*4... i.e. unit = ug*4 + (c>>2),
// gate = c&3 — full K=512 accumulated in ONE acc per wave, so the gate
// pre-activations are complete in-register after h-MFMA. The (gate x
// batch-sub) redistribution is an in-register 4x4 quad transpose via
// shfl_xor (8 shfls), not LDS.
//
// h-exchange protocol: IDENTICAL semantics to R8 (proven): dword =
// (bf16 h | step_seq16<<16), seq = s+1; flagless early-burst poll issued at
// B1, checked after x-MFMA; stale -> tight reload (1 RT/iter). Reads are
// dwordx4 (16B) now — 4 embedded seqs verified per load. Ping-pong x2.
// Critical-path discipline (R7): x(t+1) prefetch issued AFTER the poll;
// out-store plain cached.
// ---------------------------------------------------------------------------
__global__ __launch_bounds__(512) void lstm_persist(
    const float* __restrict__ X,           // [1024, 32, 512]
    const float* __restrict__ Wih,         // [2048, 512]
    const float* __restrict__ Whh,         // [2048, 512]
    const float* __restrict__ bih,         // [2048]
    const float* __restrict__ bhh,         // [2048]
    float* __restrict__ out,               // [1024*32*512]
    unsigned* __restrict__ hw,             // [2][2][32][512] dwords (h|seq)
    float* __restrict__ obwd) {            // bwd out buffer (split) or null
  __shared__ unsigned short xs[32][520];   // staged x(t) bf16, +8 pad
  __shared__ unsigned short hs[32][520];   // staged h(s-1) bf16, +8 pad

  const int tid = threadIdx.x;
  const int bid = blockIdx.x;
  const int dir = bid >> 5;
  const int bsl = bid & 31;
  const int u0 = bsl * 16;

  unsigned* hwD = hw + dir * 2 * (BATCH * HID);   // per-direction dword region

  const int w = tid >> 6, lane = tid & 63;
  const int mh = w >> 2;          // batch half (0..1)
  const int ug = w & 3;           // unit group (4 units)
  const int colx = lane & 15, q = lane >> 4;
  const int g = colx & 3;         // quad pos: gate col at MFMA, batch-sub after transpose
  const int ul = colx >> 2;       // unit within group
  const int unit = u0 + ug * 4 + ul;        // global hidden unit of this lane
  const int b_lane = mh * 16 + q * 4 + g;   // batch row of this lane (post-transpose)

  // Preload full-K B-fragments: W row = gate(g)*HID + unit, K = 512.
  short8 bwh[16], bwx[16];
  {
    const size_t roff = (size_t)(g * HID + unit) * KDIM + q * 8;
    const float* wrh = Whh + roff;
    const float* wrx = Wih + roff;
#pragma unroll
    for (int ks = 0; ks < 16; ++ks) {
      float4 h0 = *(const float4*)(wrh + ks * 32);
      float4 h1 = *(const float4*)(wrh + ks * 32 + 4);
      union { unsigned short u[8]; short8 v; } pk;
      pk.u[0] = f2bf(h0.x); pk.u[1] = f2bf(h0.y); pk.u[2] = f2bf(h0.z); pk.u[3] = f2bf(h0.w);
      pk.u[4] = f2bf(h1.x); pk.u[5] = f2bf(h1.y); pk.u[6] = f2bf(h1.z); pk.u[7] = f2bf(h1.w);
      bwh[ks] = pk.v;
      float4 x0 = *(const float4*)(wrx + ks * 32);
      float4 x1 = *(const float4*)(wrx + ks * 32 + 4);
      union { unsigned short u[8]; short8 v; } px;
      px.u[0] = f2bf(x0.x); px.u[1] = f2bf(x0.y); px.u[2] = f2bf(x0.z); px.u[3] = f2bf(x0.w);
      px.u[4] = f2bf(x1.x); px.u[5] = f2bf(x1.y); px.u[6] = f2bf(x1.z); px.u[7] = f2bf(x1.w);
      bwx[ks] = px.v;
    }
  }

  // Per-lane biases: all 4 gates of this lane's unit.
  const float bias0 = bih[0 * HID + unit] + bhh[0 * HID + unit];
  const float bias1 = bih[1 * HID + unit] + bhh[1 * HID + unit];
  const float bias2 = bih[2 * HID + unit] + bhh[2 * HID + unit];
  const float bias3 = bih[3 * HID + unit] + bhh[3 * HID + unit];

  float c_st = 0.f, h_prev = 0.f;

  float* odst = nullptr;
  if (obwd) odst = dir ? obwd : out;   // split-store mode

  // ---- prologue: prefetch x(t0) into registers ----
  float4 xr[8];
  {
    const int t0 = dir ? (T_STEPS - 1) : 0;
    const float* xt = X + (size_t)t0 * BATCH * KDIM;
#pragma unroll
    for (int r = 0; r < 8; ++r) {
      int idx = tid + r * 512;
      xr[r] = *(const float4*)(xt + (size_t)(idx >> 7) * KDIM + (idx & 127) * 4);
    }
  }

  for (int s = 0; s < T_STEPS; ++s) {
    const int t = dir ? (T_STEPS - 1 - s) : s;

    // ---- convert prefetched x(t) -> LDS bf16 ----
#pragma unroll
    for (int r = 0; r < 8; ++r) {
      int idx = tid + r * 512;
      union { unsigned short u[4]; uint2 v; } p;
      p.u[0] = f2bf(xr[r].x); p.u[1] = f2bf(xr[r].y);
      p.u[2] = f2bf(xr[r].z); p.u[3] = f2bf(xr[r].w);
      *(uint2*)&xs[idx >> 7][(idx & 127) * 4] = p.v;
    }
    __syncthreads();   // B1

    // ---- issue the h(s-1) poll burst EARLY: flies under x-MFMA ----
    const unsigned* hq = hwD + (s & 1) * (BATCH * HID);
    int4v v[8];
    issue_burst(hq, tid, v);

    // ---- x-projection MFMAs, full K (LDS-only; burst in flight) ----
    floatx4 acc = {0.f, 0.f, 0.f, 0.f};
    {
      const unsigned short* ap = &xs[mh * 16 + colx][q * 8];
#pragma unroll
      for (int ks = 0; ks < 16; ++ks) {
        short8 a = *(const short8*)(ap + ks * 32);
        acc = __builtin_amdgcn_mfma_f32_16x16x32_bf16(a, bwx[ks], acc, 0, 0, 0);
      }
    }

    // ---- wait + check burst; stale -> tight reload-all (1 RT/iter) ----
    waitv0();
    __builtin_amdgcn_sched_barrier(0);   // rule #18: pin reads after the wait
    {
      const unsigned rep = (unsigned)s << 16;
      for (;;) {
        unsigned bad = 0;
#pragma unroll
        for (int gg = 0; gg < 8; ++gg) {
          bad |= ((unsigned)v[gg].x ^ rep);
          bad |= ((unsigned)v[gg].y ^ rep);
          bad |= ((unsigned)v[gg].z ^ rep);
          bad |= ((unsigned)v[gg].w ^ rep);
        }
        if (!(bad & 0xFFFF0000u)) break;
        issue_burst(hq, tid, v);
        waitv0();
        __builtin_amdgcn_sched_barrier(0);
      }
    }

    // ---- NOW issue x(t+1) prefetch (hides under stage/h-MFMA/pointwise;
    //      waited at next step's convert — vmcnt ordering keeps it off the
    //      poll's critical path) ----
    {
      const int sn = (s + 1 < T_STEPS) ? (s + 1) : s;
      const int tn = dir ? (T_STEPS - 1 - sn) : sn;
      const float* xt = X + (size_t)tn * BATCH * KDIM;
#pragma unroll
      for (int r = 0; r < 8; ++r) {
        int idx = tid + r * 512;
        xr[r] = *(const float4*)(xt + (size_t)(idx >> 7) * KDIM + (idx & 127) * 4);
      }
    }

    // ---- stage h(s-1) -> LDS (pack 4 low-halves per 16B read) ----
#pragma unroll
    for (int gg = 0; gg < 8; ++gg) {
      int c = tid + gg * 512;               // dwordx4 chunk index 0..4095
      int row = c >> 7;                     // batch
      int col = (c & 127) << 2;             // unit column
      uint2 pk;
      pk.x = ((unsigned)v[gg].x & 0xFFFFu) | ((unsigned)v[gg].y << 16);
      pk.y = ((unsigned)v[gg].z & 0xFFFFu) | ((unsigned)v[gg].w << 16);
      *(uint2*)&hs[row][col] = pk;
    }
    __syncthreads();   // B2 (stage complete before h-MFMA reads)

    // ---- h-projection MFMAs, full K ----
    {
      const unsigned short* ap = &hs[mh * 16 + colx][q * 8];
#pragma unroll
      for (int ks = 0; ks < 16; ++ks) {
        short8 a = *(const short8*)(ap + ks * 32);
        acc = __builtin_amdgcn_mfma_f32_16x16x32_bf16(a, bwh[ks], acc, 0, 0, 0);
      }
    }

    // ---- in-register 4x4 quad transpose (gates <-> batch-subs) ----
    // Before: lane(quad-pos g) holds gate g for batches q*4+0..3 (acc[r]).
    // After : lane(quad-pos g) holds gates 0..3 (f0..f3) for batch q*4+g.
    float f0, f1, f2, f3;
    {
      float u0s = __shfl_xor(acc[0], 2), u1s = __shfl_xor(acc[1], 2);
      float u2s = __shfl_xor(acc[2], 2), u3s = __shfl_xor(acc[3], 2);
      bool hi = (g & 2) != 0;
      float w0 = hi ? u2s : acc[0];
      float w1 = hi ? u3s : acc[1];
      float w2 = hi ? acc[2] : u0s;
      float w3 = hi ? acc[3] : u1s;
      float z0 = __shfl_xor(w0, 1), z1 = __shfl_xor(w1, 1);
      float z2 = __shfl_xor(w2, 1), z3 = __shfl_xor(w3, 1);
      bool od = (g & 1) != 0;
      f0 = od ? z1 : w0;
      f1 = od ? w1 : z0;
      f2 = od ? z3 : w2;
      f3 = od ? w3 : z2;
    }

    // ---- pointwise LSTM cell + zoneout (per-lane: batch b_lane, unit) ----
    float gi = f0 + bias0;
    float gf = f1 + bias1;
    float gg2 = f2 + bias2;
    float go = f3 + bias3;
    float si = fsigmoid(gi);
    float sf = fsigmoid(gf);
    float tg = ftanh(gg2);
    float so = fsigmoid(go);
    float c_new = sf * c_st + si * tg;
    float h_new = so * ftanh(c_new);
    c_st = 0.9f * c_new + 0.1f * c_st;
    float h = 0.9f * h_new + 0.1f * h_prev;
    h_prev = h;

    // ---- publish h: per-lane (h|seq) dword, agent-scope (R8-proven) ----
    {
      unsigned D = (unsigned)f2bf(h) | ((unsigned)(s + 1) << 16);
      unsigned* hop = hwD + ((s + 1) & 1) * (BATCH * HID);
      __hip_atomic_store(&hop[b_lane * HID + unit], D,
                         __ATOMIC_RELAXED, __HIP_MEMORY_SCOPE_AGENT);
    }

    // off the critical path: output write (plain cached store: L2 ack only)
    {
      size_t oidx = (size_t)(t * BATCH + b_lane) * HID + unit;
      if (odst) odst[oidx] = h;
      else atomicAdd(out + oidx, h);   // fallback: tiny workspace
    }
  }
}

// ---------------------------------------------------------------------------
extern "C" void kernel_launch(void* const* d_in, const int* in_sizes, int n_in,
                              void* d_out, int out_size, void* d_ws, size_t ws_size,
                              hipStream_t stream) {
  const float* X   = (const float*)d_in[0];
  const float* Wih = (const float*)d_in[1];
  const float* Whh = (const float*)d_in[2];
  const float* bih = (const float*)d_in[3];
  const float* bhh = (const float*)d_in[4];
  float* out = (float*)d_out;

  // workspace layout:
  //   [0, 256KB):      hw = [2 dir][2 buf][32][512] (h|seq) dwords (256 KB)
  //   [1MB, 65MB):     bwd-direction output buffer (split-store mode)
  unsigned* hw = (unsigned*)d_ws;                     // 65536 dwords

  const size_t OB_OFF = (size_t)1 << 20;
  const size_t OB_BYTES = (size_t)T_STEPS * BATCH * HID * sizeof(float); // 64MB

  float* obwd = nullptr;
  if (ws_size >= OB_OFF + OB_BYTES)
    obwd = (float*)((char*)d_ws + OB_OFF);

  if (!obwd)   // fallback: atomicAdd accumulation needs zeroed out
    hipMemsetAsync(d_out, 0, (size_t)out_size * sizeof(float), stream);

  hipLaunchKernelGGL(init_kernel, dim3(256), dim3(256), 0, stream, hw);
  hipLaunchKernelGGL(lstm_persist, dim3(64), dim3(512), 0, stream,
                     X, Wih, Whh, bih, bhh, out, hw, obwd);
  if (obwd)
    hipLaunchKernelGGL(merge_kernel, dim3(2048), dim3(256), 0, stream,
                       out, obwd, (T_STEPS * BATCH * HID) / 4);
}